// Round 6
// baseline (641.397 us; speedup 1.0000x reference)
//
#include <hip/hip_runtime.h>

#define BB   2
#define TT   512
#define NF   6
#define DD   32
#define HIDD 128
#define NHH  4
#define HDD  32
#define GHH  32
#define FDD  128
#define LL   (TT*NF)      // 3072
#define EPSF 1e-5f
#define NQT32 96          // 32-row q-tiles per (b,h)

// ---------------------------------------------------------------------------
// Kernel 1: gater + gated QKV, 4 tokens per 64-thread block (1536 blocks).
// Q/K/V written HEAD-MAJOR: [b, h, L, 32] for contiguous attn tile loads.
// ---------------------------------------------------------------------------
__global__ __launch_bounds__(64) void gate_qkv_kernel(
    const float* __restrict__ x,
    const float* __restrict__ g_ln_w, const float* __restrict__ g_ln_b,
    const float* __restrict__ g_w1,   const float* __restrict__ g_b1,
    const float* __restrict__ g_w2,   const float* __restrict__ g_b2,
    const float* __restrict__ q_w,    const float* __restrict__ q_b,
    const float* __restrict__ k_w,    const float* __restrict__ k_b,
    const float* __restrict__ v_w,    const float* __restrict__ v_b,
    float* __restrict__ Q, float* __restrict__ K, float* __restrict__ V)
{
    const int tok0 = blockIdx.x * 4;
    const int lane = threadIdx.x;

    __shared__ float xs[4][DD];
    __shared__ float lns[4][DD];
    __shared__ float hs[4][GHH];
    __shared__ float gate_s[4];

    #pragma unroll
    for (int i = 0; i < 2; i++) {
        int idx = lane + i * 64;
        xs[idx >> 5][idx & 31] = x[(size_t)tok0 * DD + idx];
    }
    __syncthreads();

    const int tk = lane >> 5;
    const int d5 = lane & 31;

    #pragma unroll
    for (int tt = 0; tt < 2; tt++) {
        int t = tt * 2 + tk;
        float xv = xs[t][d5];
        float s1 = xv, s2 = xv * xv;
        #pragma unroll
        for (int m = 16; m >= 1; m >>= 1) {
            s1 += __shfl_xor(s1, m, 32);
            s2 += __shfl_xor(s2, m, 32);
        }
        float mu  = s1 * (1.0f / DD);
        float var = s2 * (1.0f / DD) - mu * mu;
        float r   = rsqrtf(var + EPSF);
        lns[t][d5] = (xv - mu) * r * g_ln_w[d5] + g_ln_b[d5];
    }
    __syncthreads();

    #pragma unroll
    for (int tt = 0; tt < 2; tt++) {
        int t = tt * 2 + tk;
        float acc = g_b1[d5];
        #pragma unroll
        for (int d = 0; d < DD; d++) acc += lns[t][d] * g_w1[d * GHH + d5];
        hs[t][d5] = acc / (1.0f + __expf(-acc));
    }
    __syncthreads();

    #pragma unroll
    for (int tt = 0; tt < 2; tt++) {
        int t = tt * 2 + tk;
        float p = hs[t][d5] * g_w2[d5];
        #pragma unroll
        for (int m = 16; m >= 1; m >>= 1) p += __shfl_xor(p, m, 32);
        if (d5 == 0) gate_s[t] = 1.0f / (1.0f + __expf(-(p + g_b2[0])));
    }
    __syncthreads();

    float aq0[4], aq1[4], ak0[4], ak1[4], av0[4], av1[4];
    #pragma unroll
    for (int t = 0; t < 4; t++) {
        aq0[t] = q_b[lane]; aq1[t] = q_b[lane + 64];
        ak0[t] = k_b[lane]; ak1[t] = k_b[lane + 64];
        av0[t] = v_b[lane]; av1[t] = v_b[lane + 64];
    }
    #pragma unroll
    for (int d = 0; d < DD; d++) {
        float wq0 = q_w[d * HIDD + lane], wq1 = q_w[d * HIDD + lane + 64];
        float wk0 = k_w[d * HIDD + lane], wk1 = k_w[d * HIDD + lane + 64];
        float wv0 = v_w[d * HIDD + lane], wv1 = v_w[d * HIDD + lane + 64];
        #pragma unroll
        for (int t = 0; t < 4; t++) {
            float xd = xs[t][d];
            aq0[t] += xd * wq0; aq1[t] += xd * wq1;
            ak0[t] += xd * wk0; ak1[t] += xd * wk1;
            av0[t] += xd * wv0; av1[t] += xd * wv1;
        }
    }

    const int b  = tok0 / LL;
    const int l0 = tok0 - b * LL;
    const int hA = lane >> 5;
    #pragma unroll
    for (int t = 0; t < 4; t++) {
        float g = gate_s[t];
        size_t p0 = ((size_t)(b * NHH + hA)     * LL + l0 + t) * HDD + d5;
        size_t p1 = ((size_t)(b * NHH + 2 + hA) * LL + l0 + t) * HDD + d5;
        Q[p0] = aq0[t] * g;  Q[p1] = aq1[t] * g;
        K[p0] = ak0[t] * g;  K[p1] = ak1[t] * g;
        V[p0] = av0[t] * g;  V[p1] = av1[t] * g;
    }
}

// ---------------------------------------------------------------------------
// Kernel 2: flash attention, 4-wave blocks, in-block key split.
// Block = (qt: 32 q-rows, bh). 4 waves share LDS K/V windows of 128 keys;
// wave w consumes keys [w*32, w*32+32) of each window with private online
// softmax state; partials merged in LDS at block end (flash-decoding math).
// Lane = (g: 4-row group, kp: key parity, sl: 8-dim slice) — each LDS read
// serves 4 q-rows -> 16 (row,key) pairs per ds_read_b128 (4x fewer LDS
// instrs than the R2 kernel, which was LDS-pipe-bound at ~184 us).
// Causal prefix: row i attends exactly j < 6*(i/6+1).
// ---------------------------------------------------------------------------
__global__ __launch_bounds__(256) void attn_kernel(
    const float* __restrict__ Q, const float* __restrict__ K,
    const float* __restrict__ V, float* __restrict__ O)
{
    const int qt   = (NQT32 - 1) - blockIdx.x;   // 95..0, heavy first
    const int bh   = blockIdx.y;                 // b*4 + h
    const int tid  = threadIdx.x;
    const int w    = tid >> 6;                   // wave 0..3
    const int lane = tid & 63;
    const int g    = lane >> 3;                  // row group 0..7
    const int kp   = (lane >> 2) & 1;            // key parity
    const int sl   = lane & 3;                   // dim slice (8 dims)

    // one buffer, manual layout (stride 36 floats = 144 B, 16B-aligned rows):
    // [0,4608)  : K tile, 128 rows
    // [4608,9216): V tile, 128 rows
    // after compute, [0,4608) is reused for the 4-wave merge (4*32 rows).
    __shared__ __align__(16) float smem[9216];
    float* Kt = smem;
    float* Vt = smem + 4608;

    const size_t hb  = (size_t)bh * LL;
    const int    ig0 = qt * 32 + g * 4;

    const float scale = 0.17677669529663688f;    // 1/sqrt(32)
    float q[4][8], o[4][8], m[4], l[4];
    int   jend[4];
    #pragma unroll
    for (int r = 0; r < 4; r++) {
        const int ig = ig0 + r;
        const float4* qp = (const float4*)(Q + (hb + ig) * HDD + sl * 8);
        float4 a = qp[0], b = qp[1];
        q[r][0]=a.x*scale; q[r][1]=a.y*scale; q[r][2]=a.z*scale; q[r][3]=a.w*scale;
        q[r][4]=b.x*scale; q[r][5]=b.y*scale; q[r][6]=b.z*scale; q[r][7]=b.w*scale;
        #pragma unroll
        for (int d = 0; d < 8; d++) o[r][d] = 0.0f;
        m[r] = -1e30f; l[r] = 0.0f;
        jend[r] = (ig / NF + 1) * NF;            // global exclusive prefix end
    }

    const int jmax_blk = ((qt * 32 + 31) / NF + 1) * NF;
    const int nwin     = (jmax_blk + 127) >> 7;  // 128-key windows (uniform/block)
    const int kbase    = w * 32;

    for (int win = 0; win < nwin; win++) {
        const int j0 = win << 7;
        __syncthreads();
        #pragma unroll
        for (int i = 0; i < 4; i++) {
            int slot = tid + i * 256;            // 0..1023
            int jr = slot >> 3, c4 = slot & 7;
            const size_t gb = (hb + j0 + jr) * HDD;
            *((float4*)(Kt + jr * 36) + c4) = *((const float4*)(K + gb) + c4);
            *((float4*)(Vt + jr * 36) + c4) = *((const float4*)(V + gb) + c4);
        }
        __syncthreads();

        #pragma unroll
        for (int bb = 0; bb < 2; bb++) {
            float p[4][8];
            #pragma unroll
            for (int u = 0; u < 8; u++) {
                const int jl = kbase + bb * 16 + u * 2 + kp;
                const float4 k0 = *(const float4*)(Kt + jl * 36 + sl * 8);
                const float4 k1 = *(const float4*)(Kt + jl * 36 + sl * 8 + 4);
                #pragma unroll
                for (int r = 0; r < 4; r++) {
                    p[r][u] = q[r][0]*k0.x + q[r][1]*k0.y + q[r][2]*k0.z + q[r][3]*k0.w
                            + q[r][4]*k1.x + q[r][5]*k1.y + q[r][6]*k1.z + q[r][7]*k1.w;
                }
            }
            #pragma unroll
            for (int r = 0; r < 4; r++)
                #pragma unroll
                for (int u = 0; u < 8; u++) {
                    float t = p[r][u];
                    t += __shfl_xor(t, 1);
                    t += __shfl_xor(t, 2);
                    p[r][u] = t;
                }
            #pragma unroll
            for (int r = 0; r < 4; r++) {
                const int je = jend[r] - j0;     // window-local valid bound
                float mx = m[r];
                #pragma unroll
                for (int u = 0; u < 8; u++) {
                    const int jl = kbase + bb * 16 + u * 2 + kp;
                    float s = (jl < je) ? p[r][u] : -1e30f;
                    p[r][u] = s;
                    mx = fmaxf(mx, s);
                }
                const float corr = __expf(m[r] - mx);
                m[r] = mx;
                float ls = 0.0f;
                #pragma unroll
                for (int u = 0; u < 8; u++) {
                    const int jl = kbase + bb * 16 + u * 2 + kp;
                    float e = __expf(p[r][u] - mx);
                    e = (jl < je) ? e : 0.0f;    // kills exp(0)=1 on dead keys
                    p[r][u] = e;
                    ls += e;
                }
                l[r] = l[r] * corr + ls;
                #pragma unroll
                for (int d = 0; d < 8; d++) o[r][d] *= corr;
            }
            #pragma unroll
            for (int u = 0; u < 8; u++) {
                const int jl = kbase + bb * 16 + u * 2 + kp;
                const float4 v0 = *(const float4*)(Vt + jl * 36 + sl * 8);
                const float4 v1 = *(const float4*)(Vt + jl * 36 + sl * 8 + 4);
                #pragma unroll
                for (int r = 0; r < 4; r++) {
                    const float e = p[r][u];
                    o[r][0] += e*v0.x; o[r][1] += e*v0.y; o[r][2] += e*v0.z; o[r][3] += e*v0.w;
                    o[r][4] += e*v1.x; o[r][5] += e*v1.y; o[r][6] += e*v1.z; o[r][7] += e*v1.w;
                }
            }
        }
    }

    // merge key-parity partitions (lanes xor 4)
    #pragma unroll
    for (int r = 0; r < 4; r++) {
        float mo = __shfl_xor(m[r], 4);
        float mm = fmaxf(m[r], mo);
        float a  = __expf(m[r] - mm);
        float lw = l[r] * a;
        lw += __shfl_xor(lw, 4);
        #pragma unroll
        for (int d = 0; d < 8; d++) {
            float ow = o[r][d] * a;
            ow += __shfl_xor(ow, 4);
            o[r][d] = ow;
        }
        m[r] = mm; l[r] = lw;
    }

    // write per-wave partials into smem[0,4608) (K region, now dead)
    __syncthreads();
    if (kp == 0) {
        #pragma unroll
        for (int r = 0; r < 4; r++) {
            float* pr = smem + (size_t)(w * 32 + g * 4 + r) * 36;
            float4 w0, w1;
            w0.x=o[r][0]; w0.y=o[r][1]; w0.z=o[r][2]; w0.w=o[r][3];
            w1.x=o[r][4]; w1.y=o[r][5]; w1.z=o[r][6]; w1.w=o[r][7];
            *((float4*)(pr + sl * 8))     = w0;
            *((float4*)(pr + sl * 8 + 4)) = w1;
            if (sl == 0) { pr[32] = m[r]; pr[33] = l[r]; }
        }
    }
    __syncthreads();

    // 4-wave flash-decoding merge: thread = (row 0..31, part 0..7 -> 4 dims)
    {
        const int row  = tid >> 3;
        const int part = tid & 7;
        float M = -1e30f;
        #pragma unroll
        for (int w2 = 0; w2 < 4; w2++)
            M = fmaxf(M, smem[(size_t)(w2 * 32 + row) * 36 + 32]);
        float Lh = 0.0f;
        float ax = 0.0f, ay = 0.0f, az = 0.0f, aw = 0.0f;
        #pragma unroll
        for (int w2 = 0; w2 < 4; w2++) {
            const float* pr = smem + (size_t)(w2 * 32 + row) * 36;
            const float sc = __expf(pr[32] - M);
            Lh += pr[33] * sc;
            const float4 ov = *((const float4*)(pr + part * 4));
            ax += ov.x * sc; ay += ov.y * sc; az += ov.z * sc; aw += ov.w * sc;
        }
        const float inv = 1.0f / Lh;
        const int b = bh >> 2, h = bh & 3;
        const int ig = qt * 32 + row;
        float4 res; res.x = ax*inv; res.y = ay*inv; res.z = az*inv; res.w = aw*inv;
        *((float4*)(O + ((size_t)(b * LL + ig)) * HIDD + h * HDD + part * 4)) = res;
    }
}

// ---------------------------------------------------------------------------
// Kernel 3: mean-pool -> o-proj -> LN -> f-proj -> SiLU. Block per (t, b).
// ---------------------------------------------------------------------------
__global__ __launch_bounds__(128) void final_kernel(
    const float* __restrict__ A,
    const float* __restrict__ o_w,    const float* __restrict__ o_b,
    const float* __restrict__ f_ln_w, const float* __restrict__ f_ln_b,
    const float* __restrict__ f_w,    const float* __restrict__ f_b,
    float* __restrict__ out)
{
    const int t = blockIdx.x;
    const int b = blockIdx.y;
    const int d = threadIdx.x;

    __shared__ float ms[HIDD];
    __shared__ float lnbuf[HIDD];
    __shared__ float w1[2], w2[2];

    float acc = 0.0f;
    #pragma unroll
    for (int f = 0; f < NF; f++)
        acc += A[((size_t)(b * LL + t * NF + f)) * HIDD + d];
    acc *= (1.0f / NF);
    ms[d] = acc;
    __syncthreads();

    float ov = o_b[d];
    for (int k = 0; k < HIDD; k++) ov += ms[k] * o_w[k * HIDD + d];

    float s1 = ov, s2 = ov * ov;
    #pragma unroll
    for (int m = 32; m >= 1; m >>= 1) { s1 += __shfl_xor(s1, m); s2 += __shfl_xor(s2, m); }
    if ((d & 63) == 0) { w1[d >> 6] = s1; w2[d >> 6] = s2; }
    __syncthreads();
    float S1 = w1[0] + w1[1], S2 = w2[0] + w2[1];
    float mu  = S1 * (1.0f / HIDD);
    float var = S2 * (1.0f / HIDD) - mu * mu;
    float r   = rsqrtf(var + EPSF);
    float lnv = (ov - mu) * r * f_ln_w[d] + f_ln_b[d];
    lnbuf[d] = lnv;
    __syncthreads();

    float fv = f_b[d];
    for (int k = 0; k < HIDD; k++) fv += lnbuf[k] * f_w[k * HIDD + d];
    fv = fv / (1.0f + __expf(-fv));

    out[((size_t)(b * TT + t)) * FDD + d] = fv;
}

// ---------------------------------------------------------------------------
extern "C" void kernel_launch(void* const* d_in, const int* in_sizes, int n_in,
                              void* d_out, int out_size, void* d_ws, size_t ws_size,
                              hipStream_t stream)
{
    const float* x      = (const float*)d_in[0];
    const float* g_ln_w = (const float*)d_in[1];
    const float* g_ln_b = (const float*)d_in[2];
    const float* g_w1   = (const float*)d_in[3];
    const float* g_b1   = (const float*)d_in[4];
    const float* g_w2   = (const float*)d_in[5];
    const float* g_b2   = (const float*)d_in[6];
    const float* q_w    = (const float*)d_in[7];
    const float* q_b    = (const float*)d_in[8];
    const float* k_w    = (const float*)d_in[9];
    const float* k_b    = (const float*)d_in[10];
    const float* v_w    = (const float*)d_in[11];
    const float* v_b    = (const float*)d_in[12];
    const float* o_w    = (const float*)d_in[13];
    const float* o_b    = (const float*)d_in[14];
    const float* f_ln_w = (const float*)d_in[15];
    const float* f_ln_b = (const float*)d_in[16];
    const float* f_w    = (const float*)d_in[17];
    const float* f_b    = (const float*)d_in[18];

    const size_t stride = (size_t)BB * NHH * LL * HDD;   // 786432 floats
    float* Qw = (float*)d_ws;
    float* Kw = Qw + stride;
    float* Vw = Kw + stride;
    float* Aw = Vw + stride;                             // [B, L, HID]

    gate_qkv_kernel<<<(BB * LL) / 4, 64, 0, stream>>>(
        x, g_ln_w, g_ln_b, g_w1, g_b1, g_w2, g_b2,
        q_w, q_b, k_w, k_b, v_w, v_b, Qw, Kw, Vw);

    attn_kernel<<<dim3(NQT32, BB * NHH), 256, 0, stream>>>(Qw, Kw, Vw, Aw);

    final_kernel<<<dim3(TT, BB), 128, 0, stream>>>(
        Aw, o_w, o_b, f_ln_w, f_ln_b, f_w, f_b, (float*)d_out);
}

// Round 7
// 330.764 us; speedup vs baseline: 1.9391x; 1.9391x over previous
//
#include <hip/hip_runtime.h>

#define BB   2
#define TT   512
#define NF   6
#define DD   32
#define HIDD 128
#define NHH  4
#define HDD  32
#define GHH  32
#define FDD  128
#define LL   (TT*NF)      // 3072
#define EPSF 1e-5f
#define NQT32 96          // 32-row q-tiles per (b,h)

// Quad-local butterfly adds on the VALU pipe (DPP quad_perm), NOT ds_swizzle.
__device__ __forceinline__ float qsum1(float x) {   // x += lane^1 (within quad)
    return x + __int_as_float(__builtin_amdgcn_update_dpp(
        0, __float_as_int(x), 0xB1, 0xF, 0xF, true));
}
__device__ __forceinline__ float qsum2(float x) {   // x += lane^2 (within quad)
    return x + __int_as_float(__builtin_amdgcn_update_dpp(
        0, __float_as_int(x), 0x4E, 0xF, 0xF, true));
}

// ---------------------------------------------------------------------------
// Kernel 1: gater + gated QKV, 4 tokens per 64-thread block (1536 blocks).
// Q/K/V written HEAD-MAJOR: [b, h, L, 32].
// ---------------------------------------------------------------------------
__global__ __launch_bounds__(64) void gate_qkv_kernel(
    const float* __restrict__ x,
    const float* __restrict__ g_ln_w, const float* __restrict__ g_ln_b,
    const float* __restrict__ g_w1,   const float* __restrict__ g_b1,
    const float* __restrict__ g_w2,   const float* __restrict__ g_b2,
    const float* __restrict__ q_w,    const float* __restrict__ q_b,
    const float* __restrict__ k_w,    const float* __restrict__ k_b,
    const float* __restrict__ v_w,    const float* __restrict__ v_b,
    float* __restrict__ Q, float* __restrict__ K, float* __restrict__ V)
{
    const int tok0 = blockIdx.x * 4;
    const int lane = threadIdx.x;

    __shared__ float xs[4][DD];
    __shared__ float lns[4][DD];
    __shared__ float hs[4][GHH];
    __shared__ float gate_s[4];

    #pragma unroll
    for (int i = 0; i < 2; i++) {
        int idx = lane + i * 64;
        xs[idx >> 5][idx & 31] = x[(size_t)tok0 * DD + idx];
    }
    __syncthreads();

    const int tk = lane >> 5;
    const int d5 = lane & 31;

    #pragma unroll
    for (int tt = 0; tt < 2; tt++) {
        int t = tt * 2 + tk;
        float xv = xs[t][d5];
        float s1 = xv, s2 = xv * xv;
        #pragma unroll
        for (int m = 16; m >= 1; m >>= 1) {
            s1 += __shfl_xor(s1, m, 32);
            s2 += __shfl_xor(s2, m, 32);
        }
        float mu  = s1 * (1.0f / DD);
        float var = s2 * (1.0f / DD) - mu * mu;
        float r   = rsqrtf(var + EPSF);
        lns[t][d5] = (xv - mu) * r * g_ln_w[d5] + g_ln_b[d5];
    }
    __syncthreads();

    #pragma unroll
    for (int tt = 0; tt < 2; tt++) {
        int t = tt * 2 + tk;
        float acc = g_b1[d5];
        #pragma unroll
        for (int d = 0; d < DD; d++) acc += lns[t][d] * g_w1[d * GHH + d5];
        hs[t][d5] = acc / (1.0f + __expf(-acc));
    }
    __syncthreads();

    #pragma unroll
    for (int tt = 0; tt < 2; tt++) {
        int t = tt * 2 + tk;
        float p = hs[t][d5] * g_w2[d5];
        #pragma unroll
        for (int m = 16; m >= 1; m >>= 1) p += __shfl_xor(p, m, 32);
        if (d5 == 0) gate_s[t] = 1.0f / (1.0f + __expf(-(p + g_b2[0])));
    }
    __syncthreads();

    float aq0[4], aq1[4], ak0[4], ak1[4], av0[4], av1[4];
    #pragma unroll
    for (int t = 0; t < 4; t++) {
        aq0[t] = q_b[lane]; aq1[t] = q_b[lane + 64];
        ak0[t] = k_b[lane]; ak1[t] = k_b[lane + 64];
        av0[t] = v_b[lane]; av1[t] = v_b[lane + 64];
    }
    #pragma unroll
    for (int d = 0; d < DD; d++) {
        float wq0 = q_w[d * HIDD + lane], wq1 = q_w[d * HIDD + lane + 64];
        float wk0 = k_w[d * HIDD + lane], wk1 = k_w[d * HIDD + lane + 64];
        float wv0 = v_w[d * HIDD + lane], wv1 = v_w[d * HIDD + lane + 64];
        #pragma unroll
        for (int t = 0; t < 4; t++) {
            float xd = xs[t][d];
            aq0[t] += xd * wq0; aq1[t] += xd * wq1;
            ak0[t] += xd * wk0; ak1[t] += xd * wk1;
            av0[t] += xd * wv0; av1[t] += xd * wv1;
        }
    }

    const int b  = tok0 / LL;
    const int l0 = tok0 - b * LL;
    const int hA = lane >> 5;
    #pragma unroll
    for (int t = 0; t < 4; t++) {
        float g = gate_s[t];
        size_t p0 = ((size_t)(b * NHH + hA)     * LL + l0 + t) * HDD + d5;
        size_t p1 = ((size_t)(b * NHH + 2 + hA) * LL + l0 + t) * HDD + d5;
        Q[p0] = aq0[t] * g;  Q[p1] = aq1[t] * g;
        K[p0] = ak0[t] * g;  K[p1] = ak1[t] * g;
        V[p0] = av0[t] * g;  V[p1] = av1[t] * g;
    }
}

// ---------------------------------------------------------------------------
// Kernel 2: split-K flash-attention partials.
// Grid (96 qtiles, NCH chunks, 8 bh), block 256 = 4 waves.
// All 4 waves share the 32 q-rows and the 64-key LDS tile; wave w consumes
// keys [w*16, w*16+16) of each tile with private online-softmax state.
// Lane = (g: 4-row group, kp: key parity, sl: 8-dim slice): each K/V LDS
// read serves 4 rows (R=4 -> 0.75 LDS cyc/pair); the 4-lane dot reduction
// uses DPP quad_perm (VALU), not ds_swizzle.
// Chunk partial (o,m,l) per row -> P; merged later in final_kernel.
// ---------------------------------------------------------------------------
__global__ __launch_bounds__(256) void attn_partial(
    const float* __restrict__ Q, const float* __restrict__ K,
    const float* __restrict__ V, float* __restrict__ P,
    int C, int NCH)
{
    const int qt  = blockIdx.x;
    const int ch  = blockIdx.y;
    const int bh  = blockIdx.z;
    const int j0c = C * ch;
    const int jmax_blk = ((qt * 32 + 31) / NF + 1) * NF;
    if (j0c >= jmax_blk) return;           // dead chunk, uniform exit

    const int tid  = threadIdx.x;
    const int w    = tid >> 6;             // wave 0..3 -> key quarter
    const int lane = tid & 63;
    const int g    = lane >> 3;            // row group 0..7
    const int kp   = (lane >> 2) & 1;      // key parity
    const int sl   = lane & 3;             // dim slice (8 dims)

    __shared__ __align__(16) float smem[4608 * 2];   // K[64][36] | V[64][36]
    float* Kt = smem;
    float* Vt = smem + 4608;

    const size_t hb  = (size_t)bh * LL;
    const int    ig0 = qt * 32 + g * 4;
    const int    kb  = w * 16;

    const float scale = 0.17677669529663688f;   // 1/sqrt(32)
    float q[4][8], o[4][8], m[4], l[4];
    int   jend[4];
    #pragma unroll
    for (int r = 0; r < 4; r++) {
        const int ig = ig0 + r;
        const float4* qp = (const float4*)(Q + (hb + ig) * HDD + sl * 8);
        float4 a = qp[0], b = qp[1];
        q[r][0]=a.x*scale; q[r][1]=a.y*scale; q[r][2]=a.z*scale; q[r][3]=a.w*scale;
        q[r][4]=b.x*scale; q[r][5]=b.y*scale; q[r][6]=b.z*scale; q[r][7]=b.w*scale;
        #pragma unroll
        for (int d = 0; d < 8; d++) o[r][d] = 0.0f;
        m[r] = -1e30f; l[r] = 0.0f;
        jend[r] = (ig / NF + 1) * NF;       // global exclusive prefix end
    }

    const int nk    = min(jmax_blk - j0c, C);
    const int ntile = (nk + 63) >> 6;

    for (int kt = 0; kt < ntile; kt++) {
        const int j0 = j0c + (kt << 6);
        __syncthreads();
        #pragma unroll
        for (int i = 0; i < 4; i++) {
            int slot = tid + i * 256;       // 1024 float4 slots (64 rows x 8)
            int jr = slot >> 3, c4 = slot & 7;
            const size_t gb = (hb + j0 + jr) * HDD;
            *((float4*)(Kt + jr * 36) + c4) = *((const float4*)(K + gb) + c4);
            *((float4*)(Vt + jr * 36) + c4) = *((const float4*)(V + gb) + c4);
        }
        __syncthreads();

        float p[4][8];
        #pragma unroll
        for (int u = 0; u < 8; u++) {
            const int jl = kb + u * 2 + kp;
            const float4 k0 = *(const float4*)(Kt + jl * 36 + sl * 8);
            const float4 k1 = *(const float4*)(Kt + jl * 36 + sl * 8 + 4);
            #pragma unroll
            for (int r = 0; r < 4; r++) {
                p[r][u] = q[r][0]*k0.x + q[r][1]*k0.y + q[r][2]*k0.z + q[r][3]*k0.w
                        + q[r][4]*k1.x + q[r][5]*k1.y + q[r][6]*k1.z + q[r][7]*k1.w;
            }
        }
        // full dots via DPP quad butterfly (VALU pipe)
        #pragma unroll
        for (int r = 0; r < 4; r++)
            #pragma unroll
            for (int u = 0; u < 8; u++) p[r][u] = qsum2(qsum1(p[r][u]));

        #pragma unroll
        for (int r = 0; r < 4; r++) {
            const int je = jend[r] - j0;    // tile-local valid bound
            float mx = m[r];
            #pragma unroll
            for (int u = 0; u < 8; u++) {
                const int jl = kb + u * 2 + kp;
                float s = (jl < je) ? p[r][u] : -1e30f;
                p[r][u] = s;
                mx = fmaxf(mx, s);
            }
            const float corr = __expf(m[r] - mx);
            m[r] = mx;
            float ls = 0.0f;
            #pragma unroll
            for (int u = 0; u < 8; u++) {
                const int jl = kb + u * 2 + kp;
                float e = __expf(p[r][u] - mx);
                e = (jl < je) ? e : 0.0f;   // kill exp(0)=1 on dead keys
                p[r][u] = e;
                ls += e;
            }
            l[r] = l[r] * corr + ls;
            #pragma unroll
            for (int d = 0; d < 8; d++) o[r][d] *= corr;
        }
        #pragma unroll
        for (int u = 0; u < 8; u++) {
            const int jl = kb + u * 2 + kp;
            const float4 v0 = *(const float4*)(Vt + jl * 36 + sl * 8);
            const float4 v1 = *(const float4*)(Vt + jl * 36 + sl * 8 + 4);
            #pragma unroll
            for (int r = 0; r < 4; r++) {
                const float e = p[r][u];
                o[r][0] += e*v0.x; o[r][1] += e*v0.y; o[r][2] += e*v0.z; o[r][3] += e*v0.w;
                o[r][4] += e*v1.x; o[r][5] += e*v1.y; o[r][6] += e*v1.z; o[r][7] += e*v1.w;
            }
        }
    }

    // merge key-parity partitions (lanes ^4; once, cost negligible)
    #pragma unroll
    for (int r = 0; r < 4; r++) {
        float mo = __shfl_xor(m[r], 4);
        float mm = fmaxf(m[r], mo);
        float a  = __expf(m[r] - mm);
        float lw = l[r] * a;
        lw += __shfl_xor(lw, 4);
        #pragma unroll
        for (int d = 0; d < 8; d++) {
            float ow = o[r][d] * a;
            ow += __shfl_xor(ow, 4);
            o[r][d] = ow;
        }
        m[r] = mm; l[r] = lw;
    }

    // per-wave partials into smem (K/V region dead now): [w][32 rows][36]
    __syncthreads();
    if (kp == 0) {
        #pragma unroll
        for (int r = 0; r < 4; r++) {
            float* pr = smem + (size_t)(w * 32 + g * 4 + r) * 36;
            float4 w0, w1;
            w0.x=o[r][0]; w0.y=o[r][1]; w0.z=o[r][2]; w0.w=o[r][3];
            w1.x=o[r][4]; w1.y=o[r][5]; w1.z=o[r][6]; w1.w=o[r][7];
            *((float4*)(pr + sl * 8))     = w0;
            *((float4*)(pr + sl * 8 + 4)) = w1;
            if (sl == 0) { pr[32] = m[r]; pr[33] = l[r]; }
        }
    }
    __syncthreads();

    // 4-wave merge -> chunk partial, write P[(bh,qt,ch)][row][36]
    {
        const int row  = tid >> 3;
        const int part = tid & 7;
        float M = -1e30f;
        #pragma unroll
        for (int w2 = 0; w2 < 4; w2++)
            M = fmaxf(M, smem[(size_t)(w2 * 32 + row) * 36 + 32]);
        float Lh = 0.0f, ax = 0.0f, ay = 0.0f, az = 0.0f, aw = 0.0f;
        #pragma unroll
        for (int w2 = 0; w2 < 4; w2++) {
            const float* pr = smem + (size_t)(w2 * 32 + row) * 36;
            const float sc = __expf(pr[32] - M);
            Lh += pr[33] * sc;
            const float4 ov = *((const float4*)(pr + part * 4));
            ax += ov.x * sc; ay += ov.y * sc; az += ov.z * sc; aw += ov.w * sc;
        }
        float* dst = P + ((((size_t)bh * NQT32 + qt) * NCH + ch) * 32 + row) * 36;
        float4 res; res.x = ax; res.y = ay; res.z = az; res.w = aw;
        *((float4*)(dst + part * 4)) = res;
        if (part == 0) { dst[32] = M; dst[33] = Lh; }
    }
}

// ---------------------------------------------------------------------------
// Kernel 3: chunk-merge (flash-decoding) + mean-pool + o-proj + LN + f-proj
// + SiLU. Block per (t, b), 128 threads (one per channel). All 6 force rows
// of time t share jmax = 6(t+1), hence the same chunk count.
// ---------------------------------------------------------------------------
__global__ __launch_bounds__(128) void final_kernel(
    const float* __restrict__ P,
    const float* __restrict__ o_w,    const float* __restrict__ o_b,
    const float* __restrict__ f_ln_w, const float* __restrict__ f_ln_b,
    const float* __restrict__ f_w,    const float* __restrict__ f_b,
    float* __restrict__ out, int C, int NCH)
{
    const int t = blockIdx.x;
    const int b = blockIdx.y;
    const int d = threadIdx.x;     // 0..127
    const int h  = d >> 5;         // head
    const int hd = d & 31;         // dim within head
    const int bh = b * NHH + h;

    __shared__ float ms[HIDD];
    __shared__ float lnbuf[HIDD];
    __shared__ float w1[2], w2[2];

    const int jmax = (t + 1) * NF;
    const int nch  = min(NCH, (jmax + C - 1) / C);

    float acc = 0.0f;
    #pragma unroll
    for (int f = 0; f < NF; f++) {
        const int row = t * NF + f;
        const int qt  = row >> 5;
        const int r   = row & 31;
        float M = -1e30f, L = 0.0f, O = 0.0f;
        for (int c = 0; c < nch; c++) {
            const float* pr = P + ((((size_t)bh * NQT32 + qt) * NCH + c) * 32 + r) * 36;
            const float mc = pr[32], lc = pr[33], oc = pr[hd];
            const float mm = fmaxf(M, mc);
            const float sa = __expf(M - mm), sb = __expf(mc - mm);
            O = O * sa + oc * sb;
            L = L * sa + lc * sb;
            M = mm;
        }
        acc += O / L;
    }
    acc *= (1.0f / NF);
    ms[d] = acc;
    __syncthreads();

    float ov = o_b[d];
    for (int k = 0; k < HIDD; k++) ov += ms[k] * o_w[k * HIDD + d];

    float s1 = ov, s2 = ov * ov;
    #pragma unroll
    for (int m = 32; m >= 1; m >>= 1) { s1 += __shfl_xor(s1, m); s2 += __shfl_xor(s2, m); }
    if ((d & 63) == 0) { w1[d >> 6] = s1; w2[d >> 6] = s2; }
    __syncthreads();
    float S1 = w1[0] + w1[1], S2 = w2[0] + w2[1];
    float mu  = S1 * (1.0f / HIDD);
    float var = S2 * (1.0f / HIDD) - mu * mu;
    float r   = rsqrtf(var + EPSF);
    float lnv = (ov - mu) * r * f_ln_w[d] + f_ln_b[d];
    lnbuf[d] = lnv;
    __syncthreads();

    float fv = f_b[d];
    for (int k = 0; k < HIDD; k++) fv += lnbuf[k] * f_w[k * HIDD + d];
    fv = fv / (1.0f + __expf(-fv));

    out[((size_t)(b * TT + t)) * FDD + d] = fv;
}

// ---------------------------------------------------------------------------
extern "C" void kernel_launch(void* const* d_in, const int* in_sizes, int n_in,
                              void* d_out, int out_size, void* d_ws, size_t ws_size,
                              hipStream_t stream)
{
    const float* x      = (const float*)d_in[0];
    const float* g_ln_w = (const float*)d_in[1];
    const float* g_ln_b = (const float*)d_in[2];
    const float* g_w1   = (const float*)d_in[3];
    const float* g_b1   = (const float*)d_in[4];
    const float* g_w2   = (const float*)d_in[5];
    const float* g_b2   = (const float*)d_in[6];
    const float* q_w    = (const float*)d_in[7];
    const float* q_b    = (const float*)d_in[8];
    const float* k_w    = (const float*)d_in[9];
    const float* k_b    = (const float*)d_in[10];
    const float* v_w    = (const float*)d_in[11];
    const float* v_b    = (const float*)d_in[12];
    const float* o_w    = (const float*)d_in[13];
    const float* o_b    = (const float*)d_in[14];
    const float* f_ln_w = (const float*)d_in[15];
    const float* f_ln_b = (const float*)d_in[16];
    const float* f_w    = (const float*)d_in[17];
    const float* f_b    = (const float*)d_in[18];

    const size_t stride = (size_t)BB * NHH * LL * HDD;   // 786432 floats
    float* Qw = (float*)d_ws;
    float* Kw = Qw + stride;
    float* Vw = Kw + stride;
    float* Pw = Vw + stride;                             // split-K partials

    // chunk count from available scratch (deterministic per ws_size)
    const long long unit  = 8LL * NQT32 * 32 * 36;       // floats per chunk level
    long long avail = (long long)(ws_size / 4) - 3LL * (long long)stride;
    int NCH = (int)(avail / unit);
    if (NCH > 4) NCH = 4;
    if (NCH < 1) NCH = 1;
    const int C = 64 * ((LL + 64 * NCH - 1) / (64 * NCH));  // keys/chunk, mult of 64

    gate_qkv_kernel<<<(BB * LL) / 4, 64, 0, stream>>>(
        x, g_ln_w, g_ln_b, g_w1, g_b1, g_w2, g_b2,
        q_w, q_b, k_w, k_b, v_w, v_b, Qw, Kw, Vw);

    attn_partial<<<dim3(NQT32, NCH, BB * NHH), 256, 0, stream>>>(
        Qw, Kw, Vw, Pw, C, NCH);

    final_kernel<<<dim3(TT, BB), 128, 0, stream>>>(
        Pw, o_w, o_b, f_ln_w, f_ln_b, f_w, f_b, (float*)d_out, C, NCH);
}

// Round 8
// 256.479 us; speedup vs baseline: 2.5008x; 1.2896x over previous
//
#include <hip/hip_runtime.h>

#define BB   2
#define TT   512
#define NF   6
#define DD   32
#define HIDD 128
#define NHH  4
#define HDD  32
#define GHH  32
#define FDD  128
#define LL   (TT*NF)      // 3072
#define EPSF 1e-5f
#define NQT32 96          // 32-row q-tiles per (b,h)

// Quad-local butterfly adds on the VALU pipe (DPP quad_perm), NOT ds_swizzle.
__device__ __forceinline__ float qsum1(float x) {   // x += lane^1 (within quad)
    return x + __int_as_float(__builtin_amdgcn_update_dpp(
        0, __float_as_int(x), 0xB1, 0xF, 0xF, true));
}
__device__ __forceinline__ float qsum2(float x) {   // x += lane^2 (within quad)
    return x + __int_as_float(__builtin_amdgcn_update_dpp(
        0, __float_as_int(x), 0x4E, 0xF, 0xF, true));
}

// ---------------------------------------------------------------------------
// Kernel 1: gater + gated QKV, 4 tokens per 64-thread block (1536 blocks).
// Q/K/V written HEAD-MAJOR: [b, h, L, 32].
// ---------------------------------------------------------------------------
__global__ __launch_bounds__(64) void gate_qkv_kernel(
    const float* __restrict__ x,
    const float* __restrict__ g_ln_w, const float* __restrict__ g_ln_b,
    const float* __restrict__ g_w1,   const float* __restrict__ g_b1,
    const float* __restrict__ g_w2,   const float* __restrict__ g_b2,
    const float* __restrict__ q_w,    const float* __restrict__ q_b,
    const float* __restrict__ k_w,    const float* __restrict__ k_b,
    const float* __restrict__ v_w,    const float* __restrict__ v_b,
    float* __restrict__ Q, float* __restrict__ K, float* __restrict__ V)
{
    const int tok0 = blockIdx.x * 4;
    const int lane = threadIdx.x;

    __shared__ float xs[4][DD];
    __shared__ float lns[4][DD];
    __shared__ float hs[4][GHH];
    __shared__ float gate_s[4];

    #pragma unroll
    for (int i = 0; i < 2; i++) {
        int idx = lane + i * 64;
        xs[idx >> 5][idx & 31] = x[(size_t)tok0 * DD + idx];
    }
    __syncthreads();

    const int tk = lane >> 5;
    const int d5 = lane & 31;

    #pragma unroll
    for (int tt = 0; tt < 2; tt++) {
        int t = tt * 2 + tk;
        float xv = xs[t][d5];
        float s1 = xv, s2 = xv * xv;
        #pragma unroll
        for (int m = 16; m >= 1; m >>= 1) {
            s1 += __shfl_xor(s1, m, 32);
            s2 += __shfl_xor(s2, m, 32);
        }
        float mu  = s1 * (1.0f / DD);
        float var = s2 * (1.0f / DD) - mu * mu;
        float r   = rsqrtf(var + EPSF);
        lns[t][d5] = (xv - mu) * r * g_ln_w[d5] + g_ln_b[d5];
    }
    __syncthreads();

    #pragma unroll
    for (int tt = 0; tt < 2; tt++) {
        int t = tt * 2 + tk;
        float acc = g_b1[d5];
        #pragma unroll
        for (int d = 0; d < DD; d++) acc += lns[t][d] * g_w1[d * GHH + d5];
        hs[t][d5] = acc / (1.0f + __expf(-acc));
    }
    __syncthreads();

    #pragma unroll
    for (int tt = 0; tt < 2; tt++) {
        int t = tt * 2 + tk;
        float p = hs[t][d5] * g_w2[d5];
        #pragma unroll
        for (int m = 16; m >= 1; m >>= 1) p += __shfl_xor(p, m, 32);
        if (d5 == 0) gate_s[t] = 1.0f / (1.0f + __expf(-(p + g_b2[0])));
    }
    __syncthreads();

    float aq0[4], aq1[4], ak0[4], ak1[4], av0[4], av1[4];
    #pragma unroll
    for (int t = 0; t < 4; t++) {
        aq0[t] = q_b[lane]; aq1[t] = q_b[lane + 64];
        ak0[t] = k_b[lane]; ak1[t] = k_b[lane + 64];
        av0[t] = v_b[lane]; av1[t] = v_b[lane + 64];
    }
    #pragma unroll
    for (int d = 0; d < DD; d++) {
        float wq0 = q_w[d * HIDD + lane], wq1 = q_w[d * HIDD + lane + 64];
        float wk0 = k_w[d * HIDD + lane], wk1 = k_w[d * HIDD + lane + 64];
        float wv0 = v_w[d * HIDD + lane], wv1 = v_w[d * HIDD + lane + 64];
        #pragma unroll
        for (int t = 0; t < 4; t++) {
            float xd = xs[t][d];
            aq0[t] += xd * wq0; aq1[t] += xd * wq1;
            ak0[t] += xd * wk0; ak1[t] += xd * wk1;
            av0[t] += xd * wv0; av1[t] += xd * wv1;
        }
    }

    const int b  = tok0 / LL;
    const int l0 = tok0 - b * LL;
    const int hA = lane >> 5;
    #pragma unroll
    for (int t = 0; t < 4; t++) {
        float g = gate_s[t];
        size_t p0 = ((size_t)(b * NHH + hA)     * LL + l0 + t) * HDD + d5;
        size_t p1 = ((size_t)(b * NHH + 2 + hA) * LL + l0 + t) * HDD + d5;
        Q[p0] = aq0[t] * g;  Q[p1] = aq1[t] * g;
        K[p0] = ak0[t] * g;  K[p1] = ak1[t] * g;
        V[p0] = av0[t] * g;  V[p1] = av1[t] * g;
    }
}

// ---------------------------------------------------------------------------
// Kernel 2: split-K flash-attention partials, BARRIER-FREE main loop.
// Grid (96 qtiles, NCH chunks, 8 bh), block 256 = 4 waves.
// No LDS staging: K/V (L2-resident, 384 KB per bh) are read directly from
// global as float4; a wave-instr covers 2 contiguous keys = 256 B coalesced,
// with 8-way lane broadcast. Waves drift freely (no per-tile barriers); LDS
// is used only for the single end-of-block 4-wave merge (18 KB).
// Lane = (g: 4-row group, kp: key parity, sl: 8-dim slice); each loaded K/V
// value is reused across 4 q-rows in registers. 4-lane dot reduction via
// DPP quad_perm on the VALU pipe.
// Interior tiles (j0+64 <= jmin_blk) take a select-free fast path.
// ---------------------------------------------------------------------------
__global__ __launch_bounds__(256) void attn_partial(
    const float* __restrict__ Q, const float* __restrict__ K,
    const float* __restrict__ V, float* __restrict__ P,
    int C, int NCH)
{
    const int qt  = blockIdx.x;
    const int ch  = blockIdx.y;
    const int bh  = blockIdx.z;
    const int j0c = C * ch;
    const int jmax_blk = ((qt * 32 + 31) / NF + 1) * NF;
    if (j0c >= jmax_blk) return;           // dead chunk, uniform exit

    const int tid  = threadIdx.x;
    const int w    = tid >> 6;             // wave 0..3 -> key quarter
    const int lane = tid & 63;
    const int g    = lane >> 3;            // row group 0..7
    const int kp   = (lane >> 2) & 1;      // key parity
    const int sl   = lane & 3;             // dim slice (8 dims)

    __shared__ __align__(16) float pbuf[4 * 32 * 36];   // merge buffer only

    const size_t hb  = (size_t)bh * LL;
    const int    ig0 = qt * 32 + g * 4;
    const int    kb  = w * 16;

    const float scale = 0.17677669529663688f;   // 1/sqrt(32)
    float q[4][8], o[4][8], m[4], l[4];
    int   jend[4];
    #pragma unroll
    for (int r = 0; r < 4; r++) {
        const int ig = ig0 + r;
        const float4* qp = (const float4*)(Q + (hb + ig) * HDD + sl * 8);
        float4 a = qp[0], b = qp[1];
        q[r][0]=a.x*scale; q[r][1]=a.y*scale; q[r][2]=a.z*scale; q[r][3]=a.w*scale;
        q[r][4]=b.x*scale; q[r][5]=b.y*scale; q[r][6]=b.z*scale; q[r][7]=b.w*scale;
        #pragma unroll
        for (int d = 0; d < 8; d++) o[r][d] = 0.0f;
        m[r] = -1e30f; l[r] = 0.0f;
        jend[r] = (ig / NF + 1) * NF;       // global exclusive prefix end
    }

    const int jmin_blk = ((qt * 32) / NF + 1) * NF;  // min prefix end in block
    const int nk    = min(jmax_blk - j0c, C);
    const int ntile = (nk + 63) >> 6;

    for (int kt = 0; kt < ntile; kt++) {
        const int j0 = j0c + (kt << 6);
        const int jb = j0 + kb;             // this wave's 16-key base

        // --- K loads (16 float4, coalesced 256B per wave-instr pair) ---
        float4 kf[8][2];
        #pragma unroll
        for (int u = 0; u < 8; u++) {
            const int jl  = jb + u * 2 + kp;
            const int jcl = min(jl, LL - 1);          // clamp over-reads
            const float* kptr = K + (hb + jcl) * HDD + sl * 8;
            kf[u][0] = *((const float4*)kptr);
            kf[u][1] = *((const float4*)(kptr + 4));
        }
        // --- scores: 8-dim partial dots, 4 rows per loaded value ---
        float p[4][8];
        #pragma unroll
        for (int u = 0; u < 8; u++) {
            const float4 k0 = kf[u][0], k1 = kf[u][1];
            #pragma unroll
            for (int r = 0; r < 4; r++) {
                p[r][u] = q[r][0]*k0.x + q[r][1]*k0.y + q[r][2]*k0.z + q[r][3]*k0.w
                        + q[r][4]*k1.x + q[r][5]*k1.y + q[r][6]*k1.z + q[r][7]*k1.w;
            }
        }
        // --- V loads issued now; latency hides under butterfly+softmax ---
        float4 vf[8][2];
        #pragma unroll
        for (int u = 0; u < 8; u++) {
            const int jl  = jb + u * 2 + kp;
            const int jcl = min(jl, LL - 1);
            const float* vptr = V + (hb + jcl) * HDD + sl * 8;
            vf[u][0] = *((const float4*)vptr);
            vf[u][1] = *((const float4*)(vptr + 4));
        }
        // --- full dots via DPP quad butterfly (VALU pipe) ---
        #pragma unroll
        for (int r = 0; r < 4; r++)
            #pragma unroll
            for (int u = 0; u < 8; u++) p[r][u] = qsum2(qsum1(p[r][u]));

        if (j0 + 64 <= jmin_blk) {
            // ---------- interior tile: no masking anywhere ----------
            #pragma unroll
            for (int r = 0; r < 4; r++) {
                float mx = m[r];
                #pragma unroll
                for (int u = 0; u < 8; u++) mx = fmaxf(mx, p[r][u]);
                const float corr = __expf(m[r] - mx);
                m[r] = mx;
                float ls = 0.0f;
                #pragma unroll
                for (int u = 0; u < 8; u++) { float e = __expf(p[r][u] - mx); p[r][u] = e; ls += e; }
                l[r] = l[r] * corr + ls;
                #pragma unroll
                for (int d = 0; d < 8; d++) o[r][d] *= corr;
            }
        } else {
            // ---------- boundary tile: per-key prefix masking ----------
            #pragma unroll
            for (int r = 0; r < 4; r++) {
                const int je = jend[r] - j0;
                float mx = m[r];
                #pragma unroll
                for (int u = 0; u < 8; u++) {
                    const int jl = kb + u * 2 + kp;
                    float s = (jl < je) ? p[r][u] : -1e30f;
                    p[r][u] = s;
                    mx = fmaxf(mx, s);
                }
                const float corr = __expf(m[r] - mx);
                m[r] = mx;
                float ls = 0.0f;
                #pragma unroll
                for (int u = 0; u < 8; u++) {
                    const int jl = kb + u * 2 + kp;
                    float e = __expf(p[r][u] - mx);
                    e = (jl < je) ? e : 0.0f;   // exact 0: kills exp(0)=1 and 0*junk
                    p[r][u] = e;
                    ls += e;
                }
                l[r] = l[r] * corr + ls;
                #pragma unroll
                for (int d = 0; d < 8; d++) o[r][d] *= corr;
            }
        }
        // --- V accumulation: each vf reused across 4 rows ---
        #pragma unroll
        for (int u = 0; u < 8; u++) {
            const float4 v0 = vf[u][0], v1 = vf[u][1];
            #pragma unroll
            for (int r = 0; r < 4; r++) {
                const float e = p[r][u];
                o[r][0] += e*v0.x; o[r][1] += e*v0.y; o[r][2] += e*v0.z; o[r][3] += e*v0.w;
                o[r][4] += e*v1.x; o[r][5] += e*v1.y; o[r][6] += e*v1.z; o[r][7] += e*v1.w;
            }
        }
    }

    // merge key-parity partitions (lanes ^4)
    #pragma unroll
    for (int r = 0; r < 4; r++) {
        float mo = __shfl_xor(m[r], 4);
        float mm = fmaxf(m[r], mo);
        float a  = __expf(m[r] - mm);
        float lw = l[r] * a;
        lw += __shfl_xor(lw, 4);
        #pragma unroll
        for (int d = 0; d < 8; d++) {
            float ow = o[r][d] * a;
            ow += __shfl_xor(ow, 4);
            o[r][d] = ow;
        }
        m[r] = mm; l[r] = lw;
    }

    // per-wave partials into pbuf: [w][32 rows][36]
    if (kp == 0) {
        #pragma unroll
        for (int r = 0; r < 4; r++) {
            float* pr = pbuf + (size_t)(w * 32 + g * 4 + r) * 36;
            float4 w0, w1;
            w0.x=o[r][0]; w0.y=o[r][1]; w0.z=o[r][2]; w0.w=o[r][3];
            w1.x=o[r][4]; w1.y=o[r][5]; w1.z=o[r][6]; w1.w=o[r][7];
            *((float4*)(pr + sl * 8))     = w0;
            *((float4*)(pr + sl * 8 + 4)) = w1;
            if (sl == 0) { pr[32] = m[r]; pr[33] = l[r]; }
        }
    }
    __syncthreads();

    // 4-wave merge -> chunk partial, write P[(bh,qt,ch)][row][36]
    {
        const int row  = tid >> 3;
        const int part = tid & 7;
        float M = -1e30f;
        #pragma unroll
        for (int w2 = 0; w2 < 4; w2++)
            M = fmaxf(M, pbuf[(size_t)(w2 * 32 + row) * 36 + 32]);
        float Lh = 0.0f, ax = 0.0f, ay = 0.0f, az = 0.0f, aw = 0.0f;
        #pragma unroll
        for (int w2 = 0; w2 < 4; w2++) {
            const float* pr = pbuf + (size_t)(w2 * 32 + row) * 36;
            const float sc = __expf(pr[32] - M);
            Lh += pr[33] * sc;
            const float4 ov = *((const float4*)(pr + part * 4));
            ax += ov.x * sc; ay += ov.y * sc; az += ov.z * sc; aw += ov.w * sc;
        }
        float* dst = P + ((((size_t)bh * NQT32 + qt) * NCH + ch) * 32 + row) * 36;
        float4 res; res.x = ax; res.y = ay; res.z = az; res.w = aw;
        *((float4*)(dst + part * 4)) = res;
        if (part == 0) { dst[32] = M; dst[33] = Lh; }
    }
}

// ---------------------------------------------------------------------------
// Kernel 3: chunk-merge (flash-decoding) + mean-pool + o-proj + LN + f-proj
// + SiLU. Block per (t, b), 128 threads (one per channel).
// ---------------------------------------------------------------------------
__global__ __launch_bounds__(128) void final_kernel(
    const float* __restrict__ P,
    const float* __restrict__ o_w,    const float* __restrict__ o_b,
    const float* __restrict__ f_ln_w, const float* __restrict__ f_ln_b,
    const float* __restrict__ f_w,    const float* __restrict__ f_b,
    float* __restrict__ out, int C, int NCH)
{
    const int t = blockIdx.x;
    const int b = blockIdx.y;
    const int d = threadIdx.x;     // 0..127
    const int h  = d >> 5;         // head
    const int hd = d & 31;         // dim within head
    const int bh = b * NHH + h;

    __shared__ float ms[HIDD];
    __shared__ float lnbuf[HIDD];
    __shared__ float w1[2], w2[2];

    const int jmax = (t + 1) * NF;
    const int nch  = min(NCH, (jmax + C - 1) / C);

    float acc = 0.0f;
    #pragma unroll
    for (int f = 0; f < NF; f++) {
        const int row = t * NF + f;
        const int qt  = row >> 5;
        const int r   = row & 31;
        float M = -1e30f, L = 0.0f, O = 0.0f;
        for (int c = 0; c < nch; c++) {
            const float* pr = P + ((((size_t)bh * NQT32 + qt) * NCH + c) * 32 + r) * 36;
            const float mc = pr[32], lc = pr[33], oc = pr[hd];
            const float mm = fmaxf(M, mc);
            const float sa = __expf(M - mm), sb = __expf(mc - mm);
            O = O * sa + oc * sb;
            L = L * sa + lc * sb;
            M = mm;
        }
        acc += O / L;
    }
    acc *= (1.0f / NF);
    ms[d] = acc;
    __syncthreads();

    float ov = o_b[d];
    for (int k = 0; k < HIDD; k++) ov += ms[k] * o_w[k * HIDD + d];

    float s1 = ov, s2 = ov * ov;
    #pragma unroll
    for (int m = 32; m >= 1; m >>= 1) { s1 += __shfl_xor(s1, m); s2 += __shfl_xor(s2, m); }
    if ((d & 63) == 0) { w1[d >> 6] = s1; w2[d >> 6] = s2; }
    __syncthreads();
    float S1 = w1[0] + w1[1], S2 = w2[0] + w2[1];
    float mu  = S1 * (1.0f / HIDD);
    float var = S2 * (1.0f / HIDD) - mu * mu;
    float r   = rsqrtf(var + EPSF);
    float lnv = (ov - mu) * r * f_ln_w[d] + f_ln_b[d];
    lnbuf[d] = lnv;
    __syncthreads();

    float fv = f_b[d];
    for (int k = 0; k < HIDD; k++) fv += lnbuf[k] * f_w[k * HIDD + d];
    fv = fv / (1.0f + __expf(-fv));

    out[((size_t)(b * TT + t)) * FDD + d] = fv;
}

// ---------------------------------------------------------------------------
extern "C" void kernel_launch(void* const* d_in, const int* in_sizes, int n_in,
                              void* d_out, int out_size, void* d_ws, size_t ws_size,
                              hipStream_t stream)
{
    const float* x      = (const float*)d_in[0];
    const float* g_ln_w = (const float*)d_in[1];
    const float* g_ln_b = (const float*)d_in[2];
    const float* g_w1   = (const float*)d_in[3];
    const float* g_b1   = (const float*)d_in[4];
    const float* g_w2   = (const float*)d_in[5];
    const float* g_b2   = (const float*)d_in[6];
    const float* q_w    = (const float*)d_in[7];
    const float* q_b    = (const float*)d_in[8];
    const float* k_w    = (const float*)d_in[9];
    const float* k_b    = (const float*)d_in[10];
    const float* v_w    = (const float*)d_in[11];
    const float* v_b    = (const float*)d_in[12];
    const float* o_w    = (const float*)d_in[13];
    const float* o_b    = (const float*)d_in[14];
    const float* f_ln_w = (const float*)d_in[15];
    const float* f_ln_b = (const float*)d_in[16];
    const float* f_w    = (const float*)d_in[17];
    const float* f_b    = (const float*)d_in[18];

    const size_t stride = (size_t)BB * NHH * LL * HDD;   // 786432 floats
    float* Qw = (float*)d_ws;
    float* Kw = Qw + stride;
    float* Vw = Kw + stride;
    float* Pw = Vw + stride;                             // split-K partials

    // chunk count from available scratch (deterministic per ws_size)
    const long long unit  = 8LL * NQT32 * 32 * 36;       // floats per chunk level
    long long avail = (long long)(ws_size / 4) - 3LL * (long long)stride;
    int NCH = (int)(avail / unit);
    if (NCH > 4) NCH = 4;
    if (NCH < 1) NCH = 1;
    const int C = 64 * ((LL + 64 * NCH - 1) / (64 * NCH));  // keys/chunk, mult of 64

    gate_qkv_kernel<<<(BB * LL) / 4, 64, 0, stream>>>(
        x, g_ln_w, g_ln_b, g_w1, g_b1, g_w2, g_b2,
        q_w, q_b, k_w, k_b, v_w, v_b, Qw, Kw, Vw);

    attn_partial<<<dim3(NQT32, NCH, BB * NHH), 256, 0, stream>>>(
        Qw, Kw, Vw, Pw, C, NCH);

    final_kernel<<<dim3(TT, BB), 128, 0, stream>>>(
        Pw, o_w, o_b, f_ln_w, f_ln_b, f_w, f_b, (float*)d_out, C, NCH);
}

// Round 10
// 203.476 us; speedup vs baseline: 3.1522x; 1.2605x over previous
//
#include <hip/hip_runtime.h>
#include <hip/hip_bf16.h>

#define BB   2
#define TT   512
#define NF   6
#define DD   32
#define HIDD 128
#define NHH  4
#define HDD  32
#define GHH  32
#define FDD  128
#define LL   (TT*NF)      // 3072
#define EPSF 1e-5f
#define NQT16 (LL/16)     // 192

typedef __attribute__((ext_vector_type(8))) short  bf16x8;
typedef __attribute__((ext_vector_type(4))) float  f32x4;

#define MFMA16x16x32(a,b,c) __builtin_amdgcn_mfma_f32_16x16x32_bf16(a,b,c,0,0,0)

__device__ __forceinline__ unsigned short bfh(float f) {
    union { __hip_bfloat16 b; unsigned short u; } cv;
    cv.b = __float2bfloat16(f);
    return cv.u;
}
__device__ __forceinline__ float bff(unsigned short u) {
    return __uint_as_float(((unsigned)u) << 16);
}
__device__ __forceinline__ unsigned pk_bf16(float a, float b) {
    union { __hip_bfloat162 h2; unsigned u; } cv;
    cv.h2 = __float22bfloat162_rn(make_float2(a, b));
    return cv.u;
}
__device__ __forceinline__ bf16x8 ld8(const unsigned short* p) {
    return *reinterpret_cast<const bf16x8*>(p);
}

// ---------------------------------------------------------------------------
// Kernel 1: gater + gated QKV, 4 tokens per 64-thread block (1536 blocks).
// Emits bf16 hi/lo splits: Qh/Ql/Kh/Kl token-major [bh][tok][32]
// (Q pre-scaled by 1/sqrt(32) in fp32 before splitting) and
// Vth/Vtl TRANSPOSED [bh][dim][tok] for the PV MFMA A-operand.
// ---------------------------------------------------------------------------
__global__ __launch_bounds__(64) void gate_qkv_kernel(
    const float* __restrict__ x,
    const float* __restrict__ g_ln_w, const float* __restrict__ g_ln_b,
    const float* __restrict__ g_w1,   const float* __restrict__ g_b1,
    const float* __restrict__ g_w2,   const float* __restrict__ g_b2,
    const float* __restrict__ q_w,    const float* __restrict__ q_b,
    const float* __restrict__ k_w,    const float* __restrict__ k_b,
    const float* __restrict__ v_w,    const float* __restrict__ v_b,
    unsigned short* __restrict__ Qh, unsigned short* __restrict__ Ql,
    unsigned short* __restrict__ Kh, unsigned short* __restrict__ Kl,
    unsigned short* __restrict__ Vth, unsigned short* __restrict__ Vtl)
{
    const int tok0 = blockIdx.x * 4;
    const int lane = threadIdx.x;

    __shared__ float xs[4][DD];
    __shared__ float lns[4][DD];
    __shared__ float hs[4][GHH];
    __shared__ float gate_s[4];

    #pragma unroll
    for (int i = 0; i < 2; i++) {
        int idx = lane + i * 64;
        xs[idx >> 5][idx & 31] = x[(size_t)tok0 * DD + idx];
    }
    __syncthreads();

    const int tk = lane >> 5;
    const int d5 = lane & 31;

    #pragma unroll
    for (int tt = 0; tt < 2; tt++) {
        int t = tt * 2 + tk;
        float xv = xs[t][d5];
        float s1 = xv, s2 = xv * xv;
        #pragma unroll
        for (int m = 16; m >= 1; m >>= 1) {
            s1 += __shfl_xor(s1, m, 32);
            s2 += __shfl_xor(s2, m, 32);
        }
        float mu  = s1 * (1.0f / DD);
        float var = s2 * (1.0f / DD) - mu * mu;
        float r   = rsqrtf(var + EPSF);
        lns[t][d5] = (xv - mu) * r * g_ln_w[d5] + g_ln_b[d5];
    }
    __syncthreads();

    #pragma unroll
    for (int tt = 0; tt < 2; tt++) {
        int t = tt * 2 + tk;
        float acc = g_b1[d5];
        #pragma unroll
        for (int d = 0; d < DD; d++) acc += lns[t][d] * g_w1[d * GHH + d5];
        hs[t][d5] = acc / (1.0f + __expf(-acc));
    }
    __syncthreads();

    #pragma unroll
    for (int tt = 0; tt < 2; tt++) {
        int t = tt * 2 + tk;
        float p = hs[t][d5] * g_w2[d5];
        #pragma unroll
        for (int m = 16; m >= 1; m >>= 1) p += __shfl_xor(p, m, 32);
        if (d5 == 0) gate_s[t] = 1.0f / (1.0f + __expf(-(p + g_b2[0])));
    }
    __syncthreads();

    float aq0[4], aq1[4], ak0[4], ak1[4], av0[4], av1[4];
    #pragma unroll
    for (int t = 0; t < 4; t++) {
        aq0[t] = q_b[lane]; aq1[t] = q_b[lane + 64];
        ak0[t] = k_b[lane]; ak1[t] = k_b[lane + 64];
        av0[t] = v_b[lane]; av1[t] = v_b[lane + 64];
    }
    #pragma unroll
    for (int d = 0; d < DD; d++) {
        float wq0 = q_w[d * HIDD + lane], wq1 = q_w[d * HIDD + lane + 64];
        float wk0 = k_w[d * HIDD + lane], wk1 = k_w[d * HIDD + lane + 64];
        float wv0 = v_w[d * HIDD + lane], wv1 = v_w[d * HIDD + lane + 64];
        #pragma unroll
        for (int t = 0; t < 4; t++) {
            float xd = xs[t][d];
            aq0[t] += xd * wq0; aq1[t] += xd * wq1;
            ak0[t] += xd * wk0; ak1[t] += xd * wk1;
            av0[t] += xd * wv0; av1[t] += xd * wv1;
        }
    }

    const int b  = tok0 / LL;
    const int l0 = tok0 - b * LL;
    const int hA = lane >> 5;
    const float scale = 0.17677669529663688f;   // 1/sqrt(32), folded into Q

    unsigned short vh0[4], vl0[4], vh1[4], vl1[4];
    #pragma unroll
    for (int t = 0; t < 4; t++) {
        const float g = gate_s[t];
        const int tok = l0 + t;
        const size_t a0 = ((size_t)(b * NHH + hA)     * LL + tok) * HDD + d5;
        const size_t a1 = ((size_t)(b * NHH + 2 + hA) * LL + tok) * HDD + d5;
        float qv = aq0[t] * g * scale;
        unsigned short h = bfh(qv); Qh[a0] = h; Ql[a0] = bfh(qv - bff(h));
        qv = aq1[t] * g * scale;
        h = bfh(qv); Qh[a1] = h; Ql[a1] = bfh(qv - bff(h));
        float kv = ak0[t] * g;
        h = bfh(kv); Kh[a0] = h; Kl[a0] = bfh(kv - bff(h));
        kv = ak1[t] * g;
        h = bfh(kv); Kh[a1] = h; Kl[a1] = bfh(kv - bff(h));
        float vv = av0[t] * g;
        h = bfh(vv); vh0[t] = h; vl0[t] = bfh(vv - bff(h));
        vv = av1[t] * g;
        h = bfh(vv); vh1[t] = h; vl1[t] = bfh(vv - bff(h));
    }
    // transposed V stores: 4 consecutive tokens -> one ushort4 (8B) per array
    const size_t v0 = ((size_t)(b * NHH + hA)     * HDD + d5) * LL + l0;
    const size_t v1 = ((size_t)(b * NHH + 2 + hA) * HDD + d5) * LL + l0;
    *(ushort4*)(Vth + v0) = make_ushort4(vh0[0], vh0[1], vh0[2], vh0[3]);
    *(ushort4*)(Vtl + v0) = make_ushort4(vl0[0], vl0[1], vl0[2], vl0[3]);
    *(ushort4*)(Vth + v1) = make_ushort4(vh1[0], vh1[1], vh1[2], vh1[3]);
    *(ushort4*)(Vtl + v1) = make_ushort4(vl1[0], vl1[1], vl1[2], vl1[3]);
}

// ---------------------------------------------------------------------------
// Kernel 2: MFMA flash-attention partials (split-K chunks, barrier-free,
// zero LDS). Wave = 16 q-rows; block 256 = 4 independent waves (64 rows).
// S^T = K.Q^T via mfma_f32_16x16x32_bf16: A=K[16 keys][32 dims] (keys loaded
// in PERMUTED order kloc = 8*(m>>2)+4f+(m&3)), B=Q^T (n=lane&15=row).
// C-layout puts the query row on lane&15 -> per-lane softmax state; the two
// 16-key C-frags, cvt'd to bf16, ARE the B-operand P^T[k=quad*8+j][n=row] of
// O^T = V^T.P^T (A = transposed V, contiguous loads). No cross-lane P moves.
// NOTE: o (PV numerator) is complete per-row (MFMA contracts all 32 keys),
// and m is quad-uniform (xor16/32 max shuffles) — but l accumulates only the
// lane's 8 keys, so it MUST be summed across quads before the write (the R8
// bug: missing that reduction gave a row-dependent ~4x denominator error).
// Causal prefix: row i attends j < 6*(i/6+1); masked AFTER max, exp zeroed.
// ---------------------------------------------------------------------------
__global__ __launch_bounds__(256) void attn_mfma(
    const unsigned short* __restrict__ Qh, const unsigned short* __restrict__ Ql,
    const unsigned short* __restrict__ Kh, const unsigned short* __restrict__ Kl,
    const unsigned short* __restrict__ Vth, const unsigned short* __restrict__ Vtl,
    float* __restrict__ P, int C, int NCH)
{
    const int qt  = blockIdx.x;            // 64-row tile 0..47
    const int ch  = blockIdx.y;
    const int bh  = blockIdx.z;
    const int j0c = C * ch;
    const int jmax_blk = ((qt * 64 + 63) / NF + 1) * NF;
    if (j0c >= jmax_blk) return;           // dead chunk, uniform exit

    const int tid  = threadIdx.x;
    const int w    = tid >> 6;
    const int lane = tid & 63;
    const int rr   = lane & 15;            // query row in 16 / V-dim / B n-index
    const int quad = lane >> 4;

    const int ig0   = qt * 64 + w * 16;
    const int ig    = ig0 + rr;
    const int jend  = (ig / NF + 1) * NF;
    const int jmaxw = ((ig0 + 15) / NF + 1) * NF;
    const int jminw = (ig0 / NF + 1) * NF;

    const int kend = min(jmaxw - j0c, C);
    if (kend <= 0) return;                 // dead wave (partial never read)

    const size_t hbT = (size_t)bh * LL;
    const size_t qo  = (hbT + ig) * HDD + quad * 8;
    const bf16x8 qfh = ld8(Qh + qo);
    const bf16x8 qfl = ld8(Ql + qo);

    // permuted local key for A-frag row m=rr: frag f -> key 8*(m>>2)+4f+(m&3)
    const int kloc0 = 8 * (rr >> 2) + (rr & 3);
    const int kloc1 = kloc0 + 4;

    const size_t vb0 = ((size_t)bh * HDD + rr)      * LL;
    const size_t vb1 = ((size_t)bh * HDD + rr + 16) * LL;

    f32x4 o0 = {0.f, 0.f, 0.f, 0.f};       // O^T dims quad*4+reg
    f32x4 o1 = {0.f, 0.f, 0.f, 0.f};       // O^T dims 16+quad*4+reg
    float m = -1e30f, l = 0.f;

    const int ntile = (kend + 31) >> 5;
    for (int kt = 0; kt < ntile; kt++) {
        const int j0 = j0c + (kt << 5);

        const size_t k0o = (hbT + j0 + kloc0) * HDD + quad * 8;
        const size_t k1o = (hbT + j0 + kloc1) * HDD + quad * 8;
        bf16x8 ka0h = ld8(Kh + k0o), ka0l = ld8(Kl + k0o);
        bf16x8 ka1h = ld8(Kh + k1o), ka1l = ld8(Kl + k1o);
        // V loads issued early; latency hides under MFMA+softmax
        bf16x8 va0h = ld8(Vth + vb0 + j0 + quad * 8);
        bf16x8 va0l = ld8(Vtl + vb0 + j0 + quad * 8);
        bf16x8 va1h = ld8(Vth + vb1 + j0 + quad * 8);
        bf16x8 va1l = ld8(Vtl + vb1 + j0 + quad * 8);

        const f32x4 z = {0.f, 0.f, 0.f, 0.f};
        f32x4 s0 = MFMA16x16x32(ka0h, qfh, z);
        s0 = MFMA16x16x32(ka0h, qfl, s0);
        s0 = MFMA16x16x32(ka0l, qfh, s0);
        f32x4 s1 = MFMA16x16x32(ka1h, qfh, z);
        s1 = MFMA16x16x32(ka1h, qfl, s1);
        s1 = MFMA16x16x32(ka1l, qfh, s1);

        float e[8], mx, ls, corr;
        if (j0 + 32 <= jminw) {
            // interior tile: all keys live for every row in the wave
            mx = fmaxf(fmaxf(fmaxf(s0[0], s0[1]), fmaxf(s0[2], s0[3])),
                       fmaxf(fmaxf(s1[0], s1[1]), fmaxf(s1[2], s1[3])));
            mx = fmaxf(mx, __shfl_xor(mx, 16));
            mx = fmaxf(mx, __shfl_xor(mx, 32));
            mx = fmaxf(m, mx);
            corr = __expf(m - mx); m = mx;
            ls = 0.f;
            #pragma unroll
            for (int r2 = 0; r2 < 4; r2++) {
                float e0 = __expf(s0[r2] - mx);
                float e1 = __expf(s1[r2] - mx);
                e[r2] = e0; e[4 + r2] = e1; ls += e0 + e1;
            }
        } else {
            // boundary tile: C-frag element reg r of frag f = local key
            // 8*quad + 4f + r; mask before max, zero exp for dead keys.
            const int je = jend - j0;
            float t0[4], t1[4];
            #pragma unroll
            for (int r2 = 0; r2 < 4; r2++) {
                t0[r2] = (8 * quad + r2     < je) ? s0[r2] : -1e30f;
                t1[r2] = (8 * quad + 4 + r2 < je) ? s1[r2] : -1e30f;
            }
            mx = fmaxf(fmaxf(fmaxf(t0[0], t0[1]), fmaxf(t0[2], t0[3])),
                       fmaxf(fmaxf(t1[0], t1[1]), fmaxf(t1[2], t1[3])));
            mx = fmaxf(mx, __shfl_xor(mx, 16));
            mx = fmaxf(mx, __shfl_xor(mx, 32));
            mx = fmaxf(m, mx);
            corr = __expf(m - mx); m = mx;
            ls = 0.f;
            #pragma unroll
            for (int r2 = 0; r2 < 4; r2++) {
                float e0 = __expf(t0[r2] - mx);
                float e1 = __expf(t1[r2] - mx);
                e0 = (8 * quad + r2     < je) ? e0 : 0.f;  // kill exp(0)=1
                e1 = (8 * quad + 4 + r2 < je) ? e1 : 0.f;
                e[r2] = e0; e[4 + r2] = e1; ls += e0 + e1;
            }
        }
        l = l * corr + ls;
        #pragma unroll
        for (int i = 0; i < 4; i++) { o0[i] *= corr; o1[i] *= corr; }

        // pack P^T B-operand: element j (k=quad*8+j) = e[j]
        union { unsigned u[4]; bf16x8 v; } pb;
        pb.u[0] = pk_bf16(e[0], e[1]);
        pb.u[1] = pk_bf16(e[2], e[3]);
        pb.u[2] = pk_bf16(e[4], e[5]);
        pb.u[3] = pk_bf16(e[6], e[7]);

        o0 = MFMA16x16x32(va0h, pb.v, o0);
        o0 = MFMA16x16x32(va0l, pb.v, o0);
        o1 = MFMA16x16x32(va1h, pb.v, o1);
        o1 = MFMA16x16x32(va1l, pb.v, o1);
    }

    // *** THE R8 FIX ***: l holds only this lane's 8-key partial sums; all
    // four quads of a row share the same m scale, so the true denominator is
    // the cross-quad sum. (o needs nothing: MFMA contracted all 32 keys.)
    l += __shfl_xor(l, 16);
    l += __shfl_xor(l, 32);

    // write chunk partial: P[bh][qt16][ch][row16][36]
    float* dst = P + ((((size_t)bh * NQT16 + (ig0 >> 4)) * NCH + ch) * 16 + rr) * 36;
    *(f32x4*)(dst + quad * 4)      = o0;   // dims quad*4 .. +3
    *(f32x4*)(dst + 16 + quad * 4) = o1;   // dims 16+quad*4 .. +3
    if (quad == 0) { dst[32] = m; dst[33] = l; }
}

// ---------------------------------------------------------------------------
// Kernel 3: chunk-merge (flash-decoding) + mean-pool + o-proj + LN + f-proj
// + SiLU. Block per (t, b), 128 threads (one per channel).
// ---------------------------------------------------------------------------
__global__ __launch_bounds__(128) void final_kernel(
    const float* __restrict__ P,
    const float* __restrict__ o_w,    const float* __restrict__ o_b,
    const float* __restrict__ f_ln_w, const float* __restrict__ f_ln_b,
    const float* __restrict__ f_w,    const float* __restrict__ f_b,
    float* __restrict__ out, int C, int NCH)
{
    const int t = blockIdx.x;
    const int b = blockIdx.y;
    const int d = threadIdx.x;     // 0..127
    const int h  = d >> 5;         // head
    const int hd = d & 31;         // dim within head
    const int bh = b * NHH + h;

    __shared__ float ms[HIDD];
    __shared__ float lnbuf[HIDD];
    __shared__ float w1[2], w2[2];

    const int jmax = (t + 1) * NF;
    const int nch  = min(NCH, (jmax + C - 1) / C);

    float acc = 0.0f;
    #pragma unroll
    for (int f = 0; f < NF; f++) {
        const int row = t * NF + f;
        const int qt16 = row >> 4;
        const int r    = row & 15;
        float M = -1e30f, L = 0.0f, O = 0.0f;
        for (int c = 0; c < nch; c++) {
            const float* pr = P + ((((size_t)bh * NQT16 + qt16) * NCH + c) * 16 + r) * 36;
            const float mc = pr[32], lc = pr[33], oc = pr[hd];
            const float mm = fmaxf(M, mc);
            const float sa = __expf(M - mm), sb = __expf(mc - mm);
            O = O * sa + oc * sb;
            L = L * sa + lc * sb;
            M = mm;
        }
        acc += O / L;
    }
    acc *= (1.0f / NF);
    ms[d] = acc;
    __syncthreads();

    float ov = o_b[d];
    for (int k = 0; k < HIDD; k++) ov += ms[k] * o_w[k * HIDD + d];

    float s1 = ov, s2 = ov * ov;
    #pragma unroll
    for (int m = 32; m >= 1; m >>= 1) { s1 += __shfl_xor(s1, m); s2 += __shfl_xor(s2, m); }
    if ((d & 63) == 0) { w1[d >> 6] = s1; w2[d >> 6] = s2; }
    __syncthreads();
    float S1 = w1[0] + w1[1], S2 = w2[0] + w2[1];
    float mu  = S1 * (1.0f / HIDD);
    float var = S2 * (1.0f / HIDD) - mu * mu;
    float r   = rsqrtf(var + EPSF);
    float lnv = (ov - mu) * r * f_ln_w[d] + f_ln_b[d];
    lnbuf[d] = lnv;
    __syncthreads();

    float fv = f_b[d];
    for (int k = 0; k < HIDD; k++) fv += lnbuf[k] * f_w[k * HIDD + d];
    fv = fv / (1.0f + __expf(-fv));

    out[((size_t)(b * TT + t)) * FDD + d] = fv;
}

// ---------------------------------------------------------------------------
extern "C" void kernel_launch(void* const* d_in, const int* in_sizes, int n_in,
                              void* d_out, int out_size, void* d_ws, size_t ws_size,
                              hipStream_t stream)
{
    const float* x      = (const float*)d_in[0];
    const float* g_ln_w = (const float*)d_in[1];
    const float* g_ln_b = (const float*)d_in[2];
    const float* g_w1   = (const float*)d_in[3];
    const float* g_b1   = (const float*)d_in[4];
    const float* g_w2   = (const float*)d_in[5];
    const float* g_b2   = (const float*)d_in[6];
    const float* q_w    = (const float*)d_in[7];
    const float* q_b    = (const float*)d_in[8];
    const float* k_w    = (const float*)d_in[9];
    const float* k_b    = (const float*)d_in[10];
    const float* v_w    = (const float*)d_in[11];
    const float* v_b    = (const float*)d_in[12];
    const float* o_w    = (const float*)d_in[13];
    const float* o_b    = (const float*)d_in[14];
    const float* f_ln_w = (const float*)d_in[15];
    const float* f_ln_b = (const float*)d_in[16];
    const float* f_w    = (const float*)d_in[17];
    const float* f_b    = (const float*)d_in[18];

    const size_t ntok = (size_t)BB * NHH * LL * HDD;     // 786432 bf16 elems/array
    unsigned short* Qh  = (unsigned short*)d_ws;
    unsigned short* Ql  = Qh  + ntok;
    unsigned short* Kh  = Ql  + ntok;
    unsigned short* Kl  = Kh  + ntok;
    unsigned short* Vth = Kl  + ntok;
    unsigned short* Vtl = Vth + ntok;
    float* Pw = (float*)(Vtl + ntok);                    // split-K partials

    // chunk count from available scratch (deterministic per ws_size)
    const long long bf_floats = (long long)(6 * ntok) / 2;          // 2359296
    const long long unit = 8LL * NQT16 * 16 * 36;                   // 884736 fl/chunk
    long long avail = (long long)(ws_size / 4) - bf_floats - 4096;  // slack
    int NCH = (int)(avail / unit);
    if (NCH > 4) NCH = 4;
    if (NCH < 1) NCH = 1;
    const int C = 32 * ((LL + 32 * NCH - 1) / (32 * NCH));          // keys/chunk

    gate_qkv_kernel<<<(BB * LL) / 4, 64, 0, stream>>>(
        x, g_ln_w, g_ln_b, g_w1, g_b1, g_w2, g_b2,
        q_w, q_b, k_w, k_b, v_w, v_b, Qh, Ql, Kh, Kl, Vth, Vtl);

    attn_mfma<<<dim3(LL / 64, NCH, BB * NHH), 256, 0, stream>>>(
        Qh, Ql, Kh, Kl, Vth, Vtl, Pw, C, NCH);

    final_kernel<<<dim3(TT, BB), 128, 0, stream>>>(
        Pw, o_w, o_b, f_ln_w, f_ln_b, f_w, f_b, (float*)d_out, C, NCH);
}

// Round 11
// 200.933 us; speedup vs baseline: 3.1921x; 1.0127x over previous
//
#include <hip/hip_runtime.h>
#include <hip/hip_bf16.h>

#define BB   2
#define TT   512
#define NF   6
#define DD   32
#define HIDD 128
#define NHH  4
#define HDD  32
#define GHH  32
#define FDD  128
#define LL   (TT*NF)      // 3072
#define EPSF 1e-5f
#define NQT16 (LL/16)     // 192

typedef __attribute__((ext_vector_type(8))) short  bf16x8;
typedef __attribute__((ext_vector_type(4))) float  f32x4;

#define MFMA16x16x32(a,b,c) __builtin_amdgcn_mfma_f32_16x16x32_bf16(a,b,c,0,0,0)

__device__ __forceinline__ unsigned short bfh(float f) {
    union { __hip_bfloat16 b; unsigned short u; } cv;
    cv.b = __float2bfloat16(f);
    return cv.u;
}
__device__ __forceinline__ float bff(unsigned short u) {
    return __uint_as_float(((unsigned)u) << 16);
}
__device__ __forceinline__ unsigned pk_bf16(float a, float b) {
    union { __hip_bfloat162 h2; unsigned u; } cv;
    cv.h2 = __float22bfloat162_rn(make_float2(a, b));
    return cv.u;
}
__device__ __forceinline__ bf16x8 ld8(const unsigned short* p) {
    return *reinterpret_cast<const bf16x8*>(p);
}

// ---------------------------------------------------------------------------
// Kernel 1: gater + gated QKV, 4 tokens per 64-thread block (1536 blocks).
// Emits bf16 hi/lo splits: Qh/Ql/Kh/Kl token-major [bh][tok][32]
// (Q pre-scaled by 1/sqrt(32) in fp32 before splitting) and
// Vth/Vtl TRANSPOSED [bh][dim][tok] for the PV MFMA A-operand.
// (unchanged from R9 — proven correct)
// ---------------------------------------------------------------------------
__global__ __launch_bounds__(64) void gate_qkv_kernel(
    const float* __restrict__ x,
    const float* __restrict__ g_ln_w, const float* __restrict__ g_ln_b,
    const float* __restrict__ g_w1,   const float* __restrict__ g_b1,
    const float* __restrict__ g_w2,   const float* __restrict__ g_b2,
    const float* __restrict__ q_w,    const float* __restrict__ q_b,
    const float* __restrict__ k_w,    const float* __restrict__ k_b,
    const float* __restrict__ v_w,    const float* __restrict__ v_b,
    unsigned short* __restrict__ Qh, unsigned short* __restrict__ Ql,
    unsigned short* __restrict__ Kh, unsigned short* __restrict__ Kl,
    unsigned short* __restrict__ Vth, unsigned short* __restrict__ Vtl)
{
    const int tok0 = blockIdx.x * 4;
    const int lane = threadIdx.x;

    __shared__ float xs[4][DD];
    __shared__ float lns[4][DD];
    __shared__ float hs[4][GHH];
    __shared__ float gate_s[4];

    #pragma unroll
    for (int i = 0; i < 2; i++) {
        int idx = lane + i * 64;
        xs[idx >> 5][idx & 31] = x[(size_t)tok0 * DD + idx];
    }
    __syncthreads();

    const int tk = lane >> 5;
    const int d5 = lane & 31;

    #pragma unroll
    for (int tt = 0; tt < 2; tt++) {
        int t = tt * 2 + tk;
        float xv = xs[t][d5];
        float s1 = xv, s2 = xv * xv;
        #pragma unroll
        for (int m = 16; m >= 1; m >>= 1) {
            s1 += __shfl_xor(s1, m, 32);
            s2 += __shfl_xor(s2, m, 32);
        }
        float mu  = s1 * (1.0f / DD);
        float var = s2 * (1.0f / DD) - mu * mu;
        float r   = rsqrtf(var + EPSF);
        lns[t][d5] = (xv - mu) * r * g_ln_w[d5] + g_ln_b[d5];
    }
    __syncthreads();

    #pragma unroll
    for (int tt = 0; tt < 2; tt++) {
        int t = tt * 2 + tk;
        float acc = g_b1[d5];
        #pragma unroll
        for (int d = 0; d < DD; d++) acc += lns[t][d] * g_w1[d * GHH + d5];
        hs[t][d5] = acc / (1.0f + __expf(-acc));
    }
    __syncthreads();

    #pragma unroll
    for (int tt = 0; tt < 2; tt++) {
        int t = tt * 2 + tk;
        float p = hs[t][d5] * g_w2[d5];
        #pragma unroll
        for (int m = 16; m >= 1; m >>= 1) p += __shfl_xor(p, m, 32);
        if (d5 == 0) gate_s[t] = 1.0f / (1.0f + __expf(-(p + g_b2[0])));
    }
    __syncthreads();

    float aq0[4], aq1[4], ak0[4], ak1[4], av0[4], av1[4];
    #pragma unroll
    for (int t = 0; t < 4; t++) {
        aq0[t] = q_b[lane]; aq1[t] = q_b[lane + 64];
        ak0[t] = k_b[lane]; ak1[t] = k_b[lane + 64];
        av0[t] = v_b[lane]; av1[t] = v_b[lane + 64];
    }
    #pragma unroll
    for (int d = 0; d < DD; d++) {
        float wq0 = q_w[d * HIDD + lane], wq1 = q_w[d * HIDD + lane + 64];
        float wk0 = k_w[d * HIDD + lane], wk1 = k_w[d * HIDD + lane + 64];
        float wv0 = v_w[d * HIDD + lane], wv1 = v_w[d * HIDD + lane + 64];
        #pragma unroll
        for (int t = 0; t < 4; t++) {
            float xd = xs[t][d];
            aq0[t] += xd * wq0; aq1[t] += xd * wq1;
            ak0[t] += xd * wk0; ak1[t] += xd * wk1;
            av0[t] += xd * wv0; av1[t] += xd * wv1;
        }
    }

    const int b  = tok0 / LL;
    const int l0 = tok0 - b * LL;
    const int hA = lane >> 5;
    const float scale = 0.17677669529663688f;   // 1/sqrt(32), folded into Q

    unsigned short vh0[4], vl0[4], vh1[4], vl1[4];
    #pragma unroll
    for (int t = 0; t < 4; t++) {
        const float g = gate_s[t];
        const int tok = l0 + t;
        const size_t a0 = ((size_t)(b * NHH + hA)     * LL + tok) * HDD + d5;
        const size_t a1 = ((size_t)(b * NHH + 2 + hA) * LL + tok) * HDD + d5;
        float qv = aq0[t] * g * scale;
        unsigned short h = bfh(qv); Qh[a0] = h; Ql[a0] = bfh(qv - bff(h));
        qv = aq1[t] * g * scale;
        h = bfh(qv); Qh[a1] = h; Ql[a1] = bfh(qv - bff(h));
        float kv = ak0[t] * g;
        h = bfh(kv); Kh[a0] = h; Kl[a0] = bfh(kv - bff(h));
        kv = ak1[t] * g;
        h = bfh(kv); Kh[a1] = h; Kl[a1] = bfh(kv - bff(h));
        float vv = av0[t] * g;
        h = bfh(vv); vh0[t] = h; vl0[t] = bfh(vv - bff(h));
        vv = av1[t] * g;
        h = bfh(vv); vh1[t] = h; vl1[t] = bfh(vv - bff(h));
    }
    // transposed V stores: 4 consecutive tokens -> one ushort4 (8B) per array
    const size_t v0 = ((size_t)(b * NHH + hA)     * HDD + d5) * LL + l0;
    const size_t v1 = ((size_t)(b * NHH + 2 + hA) * HDD + d5) * LL + l0;
    *(ushort4*)(Vth + v0) = make_ushort4(vh0[0], vh0[1], vh0[2], vh0[3]);
    *(ushort4*)(Vtl + v0) = make_ushort4(vl0[0], vl0[1], vl0[2], vl0[3]);
    *(ushort4*)(Vth + v1) = make_ushort4(vh1[0], vh1[1], vh1[2], vh1[3]);
    *(ushort4*)(Vtl + v1) = make_ushort4(vl1[0], vl1[1], vl1[2], vl1[3]);
}

// ---------------------------------------------------------------------------
// Kernel 2: MFMA flash-attention partials (split-K chunks, barrier-free,
// zero LDS) — R9 core + SOFTWARE-PIPELINED PREFETCH: next tile's 8 K/V loads
// are issued before the current tile's MFMAs, so they stay in flight across
// ~all of the tile's compute (AITER-style vmcnt(8) pattern). qt reversed so
// heavy blocks launch first; NCH=6 raises live waves/CU 12 -> ~18.
// Math identical to R9 (incl. the cross-quad l reduction).
// ---------------------------------------------------------------------------
__global__ __launch_bounds__(256) void attn_mfma(
    const unsigned short* __restrict__ Qh, const unsigned short* __restrict__ Ql,
    const unsigned short* __restrict__ Kh, const unsigned short* __restrict__ Kl,
    const unsigned short* __restrict__ Vth, const unsigned short* __restrict__ Vtl,
    float* __restrict__ P, int C, int NCH)
{
    const int qt  = (LL / 64 - 1) - blockIdx.x;   // heavy prefixes first
    const int ch  = blockIdx.y;
    const int bh  = blockIdx.z;
    const int j0c = C * ch;
    const int jmax_blk = ((qt * 64 + 63) / NF + 1) * NF;
    if (j0c >= jmax_blk) return;           // dead chunk, uniform exit

    const int tid  = threadIdx.x;
    const int w    = tid >> 6;
    const int lane = tid & 63;
    const int rr   = lane & 15;            // query row in 16 / V-dim / B n-index
    const int quad = lane >> 4;

    const int ig0   = qt * 64 + w * 16;
    const int ig    = ig0 + rr;
    const int jend  = (ig / NF + 1) * NF;
    const int jmaxw = ((ig0 + 15) / NF + 1) * NF;
    const int jminw = (ig0 / NF + 1) * NF;

    const int kend = min(jmaxw - j0c, C);
    if (kend <= 0) return;                 // dead wave (partial never read)

    const size_t hbT = (size_t)bh * LL;
    const size_t qo  = (hbT + ig) * HDD + quad * 8;
    const bf16x8 qfh = ld8(Qh + qo);
    const bf16x8 qfl = ld8(Ql + qo);

    // permuted local key for A-frag row m=rr: frag f -> key 8*(m>>2)+4f+(m&3)
    const int kloc0 = 8 * (rr >> 2) + (rr & 3);
    const int kloc1 = kloc0 + 4;

    const size_t vb0 = ((size_t)bh * HDD + rr)      * LL;
    const size_t vb1 = ((size_t)bh * HDD + rr + 16) * LL;

    // stream base pointers for this wave (advance by tile stride per kt)
    const unsigned short* pKh0 = Kh  + (hbT + j0c + kloc0) * HDD + quad * 8;
    const unsigned short* pKl0 = Kl  + (hbT + j0c + kloc0) * HDD + quad * 8;
    const unsigned short* pKh1 = Kh  + (hbT + j0c + kloc1) * HDD + quad * 8;
    const unsigned short* pKl1 = Kl  + (hbT + j0c + kloc1) * HDD + quad * 8;
    const unsigned short* pVh0 = Vth + vb0 + j0c + quad * 8;
    const unsigned short* pVl0 = Vtl + vb0 + j0c + quad * 8;
    const unsigned short* pVh1 = Vth + vb1 + j0c + quad * 8;
    const unsigned short* pVl1 = Vtl + vb1 + j0c + quad * 8;

    f32x4 o0 = {0.f, 0.f, 0.f, 0.f};       // O^T dims quad*4+reg
    f32x4 o1 = {0.f, 0.f, 0.f, 0.f};       // O^T dims 16+quad*4+reg
    float m = -1e30f, l = 0.f;

    const int ntile = (kend + 31) >> 5;

    // preload tile 0
    bf16x8 ka0h = ld8(pKh0), ka0l = ld8(pKl0);
    bf16x8 ka1h = ld8(pKh1), ka1l = ld8(pKl1);
    bf16x8 va0h = ld8(pVh0), va0l = ld8(pVl0);
    bf16x8 va1h = ld8(pVh1), va1l = ld8(pVl1);

    for (int kt = 0; kt < ntile; kt++) {
        const int j0 = j0c + (kt << 5);

        // ---- prefetch next tile (clamped on last iter; value discarded) ----
        const int    kn   = (kt + 1 < ntile) ? kt + 1 : kt;
        const size_t koff = (size_t)kn * 32 * HDD;   // K: 32 tokens * 32 dims
        const size_t voff = (size_t)kn * 32;         // V^T: 32 tokens
        bf16x8 nk0h = ld8(pKh0 + koff), nk0l = ld8(pKl0 + koff);
        bf16x8 nk1h = ld8(pKh1 + koff), nk1l = ld8(pKl1 + koff);
        bf16x8 nv0h = ld8(pVh0 + voff), nv0l = ld8(pVl0 + voff);
        bf16x8 nv1h = ld8(pVh1 + voff), nv1l = ld8(pVl1 + voff);

        const f32x4 z = {0.f, 0.f, 0.f, 0.f};
        f32x4 s0 = MFMA16x16x32(ka0h, qfh, z);
        f32x4 s1 = MFMA16x16x32(ka1h, qfh, z);
        s0 = MFMA16x16x32(ka0h, qfl, s0);
        s1 = MFMA16x16x32(ka1h, qfl, s1);
        s0 = MFMA16x16x32(ka0l, qfh, s0);
        s1 = MFMA16x16x32(ka1l, qfh, s1);

        float e[8], mx, ls, corr;
        if (j0 + 32 <= jminw) {
            // interior tile: all keys live for every row in the wave
            mx = fmaxf(fmaxf(fmaxf(s0[0], s0[1]), fmaxf(s0[2], s0[3])),
                       fmaxf(fmaxf(s1[0], s1[1]), fmaxf(s1[2], s1[3])));
            mx = fmaxf(mx, __shfl_xor(mx, 16));
            mx = fmaxf(mx, __shfl_xor(mx, 32));
            mx = fmaxf(m, mx);
            corr = __expf(m - mx); m = mx;
            ls = 0.f;
            #pragma unroll
            for (int r2 = 0; r2 < 4; r2++) {
                float e0 = __expf(s0[r2] - mx);
                float e1 = __expf(s1[r2] - mx);
                e[r2] = e0; e[4 + r2] = e1; ls += e0 + e1;
            }
        } else {
            // boundary tile: C-frag element reg r of frag f = local key
            // 8*quad + 4f + r; mask before max, zero exp for dead keys.
            const int je = jend - j0;
            float t0[4], t1[4];
            #pragma unroll
            for (int r2 = 0; r2 < 4; r2++) {
                t0[r2] = (8 * quad + r2     < je) ? s0[r2] : -1e30f;
                t1[r2] = (8 * quad + 4 + r2 < je) ? s1[r2] : -1e30f;
            }
            mx = fmaxf(fmaxf(fmaxf(t0[0], t0[1]), fmaxf(t0[2], t0[3])),
                       fmaxf(fmaxf(t1[0], t1[1]), fmaxf(t1[2], t1[3])));
            mx = fmaxf(mx, __shfl_xor(mx, 16));
            mx = fmaxf(mx, __shfl_xor(mx, 32));
            mx = fmaxf(m, mx);
            corr = __expf(m - mx); m = mx;
            ls = 0.f;
            #pragma unroll
            for (int r2 = 0; r2 < 4; r2++) {
                float e0 = __expf(t0[r2] - mx);
                float e1 = __expf(t1[r2] - mx);
                e0 = (8 * quad + r2     < je) ? e0 : 0.f;  // kill exp(0)=1
                e1 = (8 * quad + 4 + r2 < je) ? e1 : 0.f;
                e[r2] = e0; e[4 + r2] = e1; ls += e0 + e1;
            }
        }
        l = l * corr + ls;
        #pragma unroll
        for (int i = 0; i < 4; i++) { o0[i] *= corr; o1[i] *= corr; }

        // pack P^T B-operand: element j (k=quad*8+j) = e[j]
        union { unsigned u[4]; bf16x8 v; } pb;
        pb.u[0] = pk_bf16(e[0], e[1]);
        pb.u[1] = pk_bf16(e[2], e[3]);
        pb.u[2] = pk_bf16(e[4], e[5]);
        pb.u[3] = pk_bf16(e[6], e[7]);

        o0 = MFMA16x16x32(va0h, pb.v, o0);
        o1 = MFMA16x16x32(va1h, pb.v, o1);
        o0 = MFMA16x16x32(va0l, pb.v, o0);
        o1 = MFMA16x16x32(va1l, pb.v, o1);

        // rotate pipeline registers
        ka0h = nk0h; ka0l = nk0l; ka1h = nk1h; ka1l = nk1l;
        va0h = nv0h; va0l = nv0l; va1h = nv1h; va1l = nv1l;
    }

    // l holds only this lane's 8-key partials; quads share the same m scale,
    // so the row denominator is the cross-quad sum (the R8 bug fix).
    l += __shfl_xor(l, 16);
    l += __shfl_xor(l, 32);

    // write chunk partial: P[bh][qt16][ch][row16][36]
    float* dst = P + ((((size_t)bh * NQT16 + (ig0 >> 4)) * NCH + ch) * 16 + rr) * 36;
    *(f32x4*)(dst + quad * 4)      = o0;   // dims quad*4 .. +3
    *(f32x4*)(dst + 16 + quad * 4) = o1;   // dims 16+quad*4 .. +3
    if (quad == 0) { dst[32] = m; dst[33] = l; }
}

// ---------------------------------------------------------------------------
// Kernel 3: chunk-merge (flash-decoding) + mean-pool + o-proj + LN + f-proj
// + SiLU. Block per (t, b), 128 threads. (unchanged from R9)
// ---------------------------------------------------------------------------
__global__ __launch_bounds__(128) void final_kernel(
    const float* __restrict__ P,
    const float* __restrict__ o_w,    const float* __restrict__ o_b,
    const float* __restrict__ f_ln_w, const float* __restrict__ f_ln_b,
    const float* __restrict__ f_w,    const float* __restrict__ f_b,
    float* __restrict__ out, int C, int NCH)
{
    const int t = blockIdx.x;
    const int b = blockIdx.y;
    const int d = threadIdx.x;     // 0..127
    const int h  = d >> 5;         // head
    const int hd = d & 31;         // dim within head
    const int bh = b * NHH + h;

    __shared__ float ms[HIDD];
    __shared__ float lnbuf[HIDD];
    __shared__ float w1[2], w2[2];

    const int jmax = (t + 1) * NF;
    const int nch  = min(NCH, (jmax + C - 1) / C);

    float acc = 0.0f;
    #pragma unroll
    for (int f = 0; f < NF; f++) {
        const int row = t * NF + f;
        const int qt16 = row >> 4;
        const int r    = row & 15;
        float M = -1e30f, L = 0.0f, O = 0.0f;
        for (int c = 0; c < nch; c++) {
            const float* pr = P + ((((size_t)bh * NQT16 + qt16) * NCH + c) * 16 + r) * 36;
            const float mc = pr[32], lc = pr[33], oc = pr[hd];
            const float mm = fmaxf(M, mc);
            const float sa = __expf(M - mm), sb = __expf(mc - mm);
            O = O * sa + oc * sb;
            L = L * sa + lc * sb;
            M = mm;
        }
        acc += O / L;
    }
    acc *= (1.0f / NF);
    ms[d] = acc;
    __syncthreads();

    float ov = o_b[d];
    for (int k = 0; k < HIDD; k++) ov += ms[k] * o_w[k * HIDD + d];

    float s1 = ov, s2 = ov * ov;
    #pragma unroll
    for (int m = 32; m >= 1; m >>= 1) { s1 += __shfl_xor(s1, m); s2 += __shfl_xor(s2, m); }
    if ((d & 63) == 0) { w1[d >> 6] = s1; w2[d >> 6] = s2; }
    __syncthreads();
    float S1 = w1[0] + w1[1], S2 = w2[0] + w2[1];
    float mu  = S1 * (1.0f / HIDD);
    float var = S2 * (1.0f / HIDD) - mu * mu;
    float r   = rsqrtf(var + EPSF);
    float lnv = (ov - mu) * r * f_ln_w[d] + f_ln_b[d];
    lnbuf[d] = lnv;
    __syncthreads();

    float fv = f_b[d];
    for (int k = 0; k < HIDD; k++) fv += lnbuf[k] * f_w[k * HIDD + d];
    fv = fv / (1.0f + __expf(-fv));

    out[((size_t)(b * TT + t)) * FDD + d] = fv;
}

// ---------------------------------------------------------------------------
extern "C" void kernel_launch(void* const* d_in, const int* in_sizes, int n_in,
                              void* d_out, int out_size, void* d_ws, size_t ws_size,
                              hipStream_t stream)
{
    const float* x      = (const float*)d_in[0];
    const float* g_ln_w = (const float*)d_in[1];
    const float* g_ln_b = (const float*)d_in[2];
    const float* g_w1   = (const float*)d_in[3];
    const float* g_b1   = (const float*)d_in[4];
    const float* g_w2   = (const float*)d_in[5];
    const float* g_b2   = (const float*)d_in[6];
    const float* q_w    = (const float*)d_in[7];
    const float* q_b    = (const float*)d_in[8];
    const float* k_w    = (const float*)d_in[9];
    const float* k_b    = (const float*)d_in[10];
    const float* v_w    = (const float*)d_in[11];
    const float* v_b    = (const float*)d_in[12];
    const float* o_w    = (const float*)d_in[13];
    const float* o_b    = (const float*)d_in[14];
    const float* f_ln_w = (const float*)d_in[15];
    const float* f_ln_b = (const float*)d_in[16];
    const float* f_w    = (const float*)d_in[17];
    const float* f_b    = (const float*)d_in[18];

    const size_t ntok = (size_t)BB * NHH * LL * HDD;     // 786432 bf16 elems/array
    unsigned short* Qh  = (unsigned short*)d_ws;
    unsigned short* Ql  = Qh  + ntok;
    unsigned short* Kh  = Ql  + ntok;
    unsigned short* Kl  = Kh  + ntok;
    unsigned short* Vth = Kl  + ntok;
    unsigned short* Vtl = Vth + ntok;
    float* Pw = (float*)(Vtl + ntok);                    // split-K partials

    // chunk count from available scratch (deterministic per ws_size)
    const long long bf_floats = (long long)(6 * ntok) / 2;          // 2359296
    const long long unit = 8LL * NQT16 * 16 * 36;                   // 884736 fl/chunk
    long long avail = (long long)(ws_size / 4) - bf_floats - 4096;  // slack
    int NCH = (int)(avail / unit);
    if (NCH > 6) NCH = 6;
    if (NCH < 1) NCH = 1;
    const int C = 32 * ((LL + 32 * NCH - 1) / (32 * NCH));          // keys/chunk

    gate_qkv_kernel<<<(BB * LL) / 4, 64, 0, stream>>>(
        x, g_ln_w, g_ln_b, g_w1, g_b1, g_w2, g_b2,
        q_w, q_b, k_w, k_b, v_w, v_b, Qh, Ql, Kh, Kl, Vth, Vtl);

    attn_mfma<<<dim3(LL / 64, NCH, BB * NHH), 256, 0, stream>>>(
        Qh, Ql, Kh, Kl, Vth, Vtl, Pw, C, NCH);

    final_kernel<<<dim3(TT, BB), 128, 0, stream>>>(
        Pw, o_w, o_b, f_ln_w, f_ln_b, f_w, f_b, (float*)d_out, C, NCH);
}

// Round 12
// 188.968 us; speedup vs baseline: 3.3942x; 1.0633x over previous
//
#include <hip/hip_runtime.h>
#include <hip/hip_bf16.h>

#define BB   2
#define TT   512
#define NF   6
#define DD   32
#define HIDD 128
#define NHH  4
#define HDD  32
#define GHH  32
#define FDD  128
#define LL   (TT*NF)      // 3072
#define EPSF 1e-5f
#define NQT16 (LL/16)     // 192

typedef __attribute__((ext_vector_type(8))) short  bf16x8;
typedef __attribute__((ext_vector_type(4))) float  f32x4;

#define MFMA16x16x32(a,b,c) __builtin_amdgcn_mfma_f32_16x16x32_bf16(a,b,c,0,0,0)

__device__ __forceinline__ unsigned short bfh(float f) {
    union { __hip_bfloat16 b; unsigned short u; } cv;
    cv.b = __float2bfloat16(f);
    return cv.u;
}
__device__ __forceinline__ float bff(unsigned short u) {
    return __uint_as_float(((unsigned)u) << 16);
}
__device__ __forceinline__ unsigned pk_bf16(float a, float b) {
    union { __hip_bfloat162 h2; unsigned u; } cv;
    cv.h2 = __float22bfloat162_rn(make_float2(a, b));
    return cv.u;
}
__device__ __forceinline__ bf16x8 ld8(const unsigned short* p) {
    return *reinterpret_cast<const bf16x8*>(p);
}

// ---------------------------------------------------------------------------
// Kernel 1: gater + gated QKV. 4 tokens per block, 128 threads (2 waves):
// each thread owns ONE output column (col = tid) -> half the weight loads
// and FMAs of the 64-thread version, 12 waves/CU. Emits bf16 hi/lo splits:
// Qh/Ql/Kh/Kl token-major [bh][tok][32] (Q pre-scaled by 1/sqrt(32)), and
// Vth/Vtl TRANSPOSED [bh][dim][tok].
// ---------------------------------------------------------------------------
__global__ __launch_bounds__(128) void gate_qkv_kernel(
    const float* __restrict__ x,
    const float* __restrict__ g_ln_w, const float* __restrict__ g_ln_b,
    const float* __restrict__ g_w1,   const float* __restrict__ g_b1,
    const float* __restrict__ g_w2,   const float* __restrict__ g_b2,
    const float* __restrict__ q_w,    const float* __restrict__ q_b,
    const float* __restrict__ k_w,    const float* __restrict__ k_b,
    const float* __restrict__ v_w,    const float* __restrict__ v_b,
    unsigned short* __restrict__ Qh, unsigned short* __restrict__ Ql,
    unsigned short* __restrict__ Kh, unsigned short* __restrict__ Kl,
    unsigned short* __restrict__ Vth, unsigned short* __restrict__ Vtl)
{
    const int tok0 = blockIdx.x * 4;
    const int tid  = threadIdx.x;

    __shared__ float xs[4][DD];
    __shared__ float lns[4][DD];
    __shared__ float hs[4][GHH];
    __shared__ float gate_s[4];

    xs[tid >> 5][tid & 31] = x[(size_t)tok0 * DD + tid];   // 128 = 4 tok x 32 d
    __syncthreads();

    // ---- gater phases on wave 0 only (uniform barriers outside guards) ----
    const int tk = (tid >> 5) & 1;
    const int d5 = tid & 31;
    if (tid < 64) {
        #pragma unroll
        for (int tt = 0; tt < 2; tt++) {
            int t = tt * 2 + tk;
            float xv = xs[t][d5];
            float s1 = xv, s2 = xv * xv;
            #pragma unroll
            for (int m = 16; m >= 1; m >>= 1) {
                s1 += __shfl_xor(s1, m, 32);
                s2 += __shfl_xor(s2, m, 32);
            }
            float mu  = s1 * (1.0f / DD);
            float var = s2 * (1.0f / DD) - mu * mu;
            float r   = rsqrtf(var + EPSF);
            lns[t][d5] = (xv - mu) * r * g_ln_w[d5] + g_ln_b[d5];
        }
    }
    __syncthreads();
    if (tid < 64) {
        #pragma unroll
        for (int tt = 0; tt < 2; tt++) {
            int t = tt * 2 + tk;
            float acc = g_b1[d5];
            #pragma unroll
            for (int d = 0; d < DD; d++) acc += lns[t][d] * g_w1[d * GHH + d5];
            hs[t][d5] = acc / (1.0f + __expf(-acc));
        }
    }
    __syncthreads();
    if (tid < 64) {
        #pragma unroll
        for (int tt = 0; tt < 2; tt++) {
            int t = tt * 2 + tk;
            float p = hs[t][d5] * g_w2[d5];
            #pragma unroll
            for (int m = 16; m >= 1; m >>= 1) p += __shfl_xor(p, m, 32);
            if (d5 == 0) gate_s[t] = 1.0f / (1.0f + __expf(-(p + g_b2[0])));
        }
    }
    __syncthreads();

    // ---- QKV projection: one column per thread ----
    const int col = tid;
    float aq[4], ak[4], av[4];
    #pragma unroll
    for (int t = 0; t < 4; t++) { aq[t] = q_b[col]; ak[t] = k_b[col]; av[t] = v_b[col]; }
    #pragma unroll
    for (int d = 0; d < DD; d++) {
        float wq = q_w[d * HIDD + col];
        float wk = k_w[d * HIDD + col];
        float wv = v_w[d * HIDD + col];
        #pragma unroll
        for (int t = 0; t < 4; t++) {
            float xd = xs[t][d];
            aq[t] += xd * wq; ak[t] += xd * wk; av[t] += xd * wv;
        }
    }

    const int b    = tok0 / LL;
    const int l0   = tok0 - b * LL;
    const int head = col >> 5;
    const int d5c  = col & 31;
    const float scale = 0.17677669529663688f;   // 1/sqrt(32), folded into Q

    unsigned short vh[4], vl[4];
    #pragma unroll
    for (int t = 0; t < 4; t++) {
        const float g = gate_s[t];
        const size_t a = ((size_t)(b * NHH + head) * LL + l0 + t) * HDD + d5c;
        float qv = aq[t] * g * scale;
        unsigned short h = bfh(qv); Qh[a] = h; Ql[a] = bfh(qv - bff(h));
        float kv = ak[t] * g;
        h = bfh(kv); Kh[a] = h; Kl[a] = bfh(kv - bff(h));
        float vv = av[t] * g;
        h = bfh(vv); vh[t] = h; vl[t] = bfh(vv - bff(h));
    }
    const size_t vbase = ((size_t)(b * NHH + head) * HDD + d5c) * LL + l0;
    *(ushort4*)(Vth + vbase) = make_ushort4(vh[0], vh[1], vh[2], vh[3]);
    *(ushort4*)(Vtl + vbase) = make_ushort4(vl[0], vl[1], vl[2], vl[3]);
}

// ---------------------------------------------------------------------------
// Kernel 2: MFMA flash-attention partials (split-K chunks, barrier-free,
// zero LDS). 1-D grid with bh = blockIdx.x & 7: under round-robin block->XCD
// dispatch all blocks of a bh land on ONE XCD, making that bh's K/V (1.2 MB)
// L2-resident (fixes R10's 24.6 MB L2-miss traffic at ~600cyc L3 latency).
// 64-key tiles: two 32-key score groups per iteration -> 16 independent
// loads and 20 MFMAs per iteration, half the softmax overhead per key.
// Layout math identical to R9/R10 (incl. the cross-quad l reduction).
// ---------------------------------------------------------------------------
__global__ __launch_bounds__(256) void attn_mfma(
    const unsigned short* __restrict__ Qh, const unsigned short* __restrict__ Ql,
    const unsigned short* __restrict__ Kh, const unsigned short* __restrict__ Kl,
    const unsigned short* __restrict__ Vth, const unsigned short* __restrict__ Vtl,
    float* __restrict__ P, int C, int NCH)
{
    const int lin = blockIdx.x;
    const int bh  = lin & 7;                    // XCD-local clustering
    const int jj  = lin >> 3;
    const int ch  = jj / (LL / 64);
    const int qt  = (LL / 64 - 1) - (jj % (LL / 64));   // heavy prefixes first
    const int j0c = C * ch;
    const int jmax_blk = ((qt * 64 + 63) / NF + 1) * NF;
    if (j0c >= jmax_blk) return;           // dead chunk, uniform exit

    const int tid  = threadIdx.x;
    const int w    = tid >> 6;
    const int lane = tid & 63;
    const int rr   = lane & 15;            // query row in 16 / V-dim / B n-index
    const int quad = lane >> 4;

    const int ig0   = qt * 64 + w * 16;
    const int ig    = ig0 + rr;
    const int jend  = (ig / NF + 1) * NF;
    const int jmaxw = ((ig0 + 15) / NF + 1) * NF;
    const int jminw = (ig0 / NF + 1) * NF;

    const int kend = min(jmaxw - j0c, C);
    if (kend <= 0) return;                 // dead wave (partial never read)

    const size_t hbT = (size_t)bh * LL;
    const size_t qo  = (hbT + ig) * HDD + quad * 8;
    const bf16x8 qfh = ld8(Qh + qo);
    const bf16x8 qfl = ld8(Ql + qo);

    // permuted local key for A-frag row m=rr: frag f -> key 8*(m>>2)+4f+(m&3)
    const int kloc0 = 8 * (rr >> 2) + (rr & 3);
    const int kloc1 = kloc0 + 4;

    const size_t vb0 = ((size_t)bh * HDD + rr)      * LL;
    const size_t vb1 = ((size_t)bh * HDD + rr + 16) * LL;

    f32x4 o0 = {0.f, 0.f, 0.f, 0.f};       // O^T dims quad*4+reg
    f32x4 o1 = {0.f, 0.f, 0.f, 0.f};       // O^T dims 16+quad*4+reg
    float m = -1e30f, l = 0.f;

    // 64-key tiles; C and LL are multiples of 64, so the tail tile's
    // over-reads stay inside [0, LL) (real tokens, masked to e=0).
    const int ntile = (kend + 63) >> 6;

    for (int kt = 0; kt < ntile; kt++) {
        const int j0 = j0c + (kt << 6);

        // ---- 16 independent loads: K groups A (j0..+31) and B (+32..+63) ----
        const size_t kA0 = (hbT + j0 + kloc0) * HDD + quad * 8;
        const size_t kA1 = (hbT + j0 + kloc1) * HDD + quad * 8;
        const size_t kB0 = kA0 + (size_t)32 * HDD;
        const size_t kB1 = kA1 + (size_t)32 * HDD;
        bf16x8 kA0h = ld8(Kh + kA0), kA0l = ld8(Kl + kA0);
        bf16x8 kA1h = ld8(Kh + kA1), kA1l = ld8(Kl + kA1);
        bf16x8 kB0h = ld8(Kh + kB0), kB0l = ld8(Kl + kB0);
        bf16x8 kB1h = ld8(Kh + kB1), kB1l = ld8(Kl + kB1);
        const size_t vA = j0 + quad * 8, vB = vA + 32;
        bf16x8 vA0h = ld8(Vth + vb0 + vA), vA0l = ld8(Vtl + vb0 + vA);
        bf16x8 vA1h = ld8(Vth + vb1 + vA), vA1l = ld8(Vtl + vb1 + vA);
        bf16x8 vB0h = ld8(Vth + vb0 + vB), vB0l = ld8(Vtl + vb0 + vB);
        bf16x8 vB1h = ld8(Vth + vb1 + vB), vB1l = ld8(Vtl + vb1 + vB);

        const f32x4 z = {0.f, 0.f, 0.f, 0.f};
        f32x4 sA0 = MFMA16x16x32(kA0h, qfh, z);
        f32x4 sA1 = MFMA16x16x32(kA1h, qfh, z);
        f32x4 sB0 = MFMA16x16x32(kB0h, qfh, z);
        f32x4 sB1 = MFMA16x16x32(kB1h, qfh, z);
        sA0 = MFMA16x16x32(kA0h, qfl, sA0);
        sA1 = MFMA16x16x32(kA1h, qfl, sA1);
        sB0 = MFMA16x16x32(kB0h, qfl, sB0);
        sB1 = MFMA16x16x32(kB1h, qfl, sB1);
        sA0 = MFMA16x16x32(kA0l, qfh, sA0);
        sA1 = MFMA16x16x32(kA1l, qfh, sA1);
        sB0 = MFMA16x16x32(kB0l, qfh, sB0);
        sB1 = MFMA16x16x32(kB1l, qfh, sB1);

        // local key index of element r: A0=8q+r, A1=8q+4+r, B0=32+8q+r, B1=36+8q+r
        float e[16], mx, ls, corr;
        if (j0 + 64 <= jminw) {
            // interior tile: every key live for every row in the wave
            f32x4 m4 = sA0;
            #pragma unroll
            for (int r2 = 0; r2 < 4; r2++) {
                m4[r2] = fmaxf(fmaxf(m4[r2], sA1[r2]), fmaxf(sB0[r2], sB1[r2]));
            }
            mx = fmaxf(fmaxf(m4[0], m4[1]), fmaxf(m4[2], m4[3]));
            mx = fmaxf(mx, __shfl_xor(mx, 16));
            mx = fmaxf(mx, __shfl_xor(mx, 32));
            mx = fmaxf(m, mx);
            corr = __expf(m - mx); m = mx;
            ls = 0.f;
            #pragma unroll
            for (int r2 = 0; r2 < 4; r2++) {
                float e0 = __expf(sA0[r2] - mx);
                float e1 = __expf(sA1[r2] - mx);
                float e2 = __expf(sB0[r2] - mx);
                float e3 = __expf(sB1[r2] - mx);
                e[r2] = e0; e[4 + r2] = e1; e[8 + r2] = e2; e[12 + r2] = e3;
                ls += (e0 + e1) + (e2 + e3);
            }
        } else {
            // boundary tile: per-key prefix masking (mask pre-max, zero exp)
            const int je = jend - j0;
            const int k0 = 8 * quad;
            float t[16];
            #pragma unroll
            for (int r2 = 0; r2 < 4; r2++) {
                t[r2]      = (k0 + r2          < je) ? sA0[r2] : -1e30f;
                t[4 + r2]  = (k0 + 4 + r2      < je) ? sA1[r2] : -1e30f;
                t[8 + r2]  = (32 + k0 + r2     < je) ? sB0[r2] : -1e30f;
                t[12 + r2] = (32 + k0 + 4 + r2 < je) ? sB1[r2] : -1e30f;
            }
            mx = t[0];
            #pragma unroll
            for (int i = 1; i < 16; i++) mx = fmaxf(mx, t[i]);
            mx = fmaxf(mx, __shfl_xor(mx, 16));
            mx = fmaxf(mx, __shfl_xor(mx, 32));
            mx = fmaxf(m, mx);
            corr = __expf(m - mx); m = mx;
            ls = 0.f;
            #pragma unroll
            for (int r2 = 0; r2 < 4; r2++) {
                float e0 = __expf(t[r2] - mx);
                float e1 = __expf(t[4 + r2] - mx);
                float e2 = __expf(t[8 + r2] - mx);
                float e3 = __expf(t[12 + r2] - mx);
                e0 = (k0 + r2          < je) ? e0 : 0.f;   // kill exp(0)=1
                e1 = (k0 + 4 + r2      < je) ? e1 : 0.f;
                e2 = (32 + k0 + r2     < je) ? e2 : 0.f;
                e3 = (32 + k0 + 4 + r2 < je) ? e3 : 0.f;
                e[r2] = e0; e[4 + r2] = e1; e[8 + r2] = e2; e[12 + r2] = e3;
                ls += (e0 + e1) + (e2 + e3);
            }
        }
        l = l * corr + ls;
        #pragma unroll
        for (int i = 0; i < 4; i++) { o0[i] *= corr; o1[i] *= corr; }

        // pack P^T B-operands: group A keys k=quad*8+j, group B same +32
        union { unsigned u[4]; bf16x8 v; } pbA, pbB;
        pbA.u[0] = pk_bf16(e[0],  e[1]);
        pbA.u[1] = pk_bf16(e[2],  e[3]);
        pbA.u[2] = pk_bf16(e[4],  e[5]);
        pbA.u[3] = pk_bf16(e[6],  e[7]);
        pbB.u[0] = pk_bf16(e[8],  e[9]);
        pbB.u[1] = pk_bf16(e[10], e[11]);
        pbB.u[2] = pk_bf16(e[12], e[13]);
        pbB.u[3] = pk_bf16(e[14], e[15]);

        o0 = MFMA16x16x32(vA0h, pbA.v, o0);
        o1 = MFMA16x16x32(vA1h, pbA.v, o1);
        o0 = MFMA16x16x32(vB0h, pbB.v, o0);
        o1 = MFMA16x16x32(vB1h, pbB.v, o1);
        o0 = MFMA16x16x32(vA0l, pbA.v, o0);
        o1 = MFMA16x16x32(vA1l, pbA.v, o1);
        o0 = MFMA16x16x32(vB0l, pbB.v, o0);
        o1 = MFMA16x16x32(vB1l, pbB.v, o1);
    }

    // l holds only this lane's 16-key-per-tile partials; quads share the same
    // m scale, so the row denominator is the cross-quad sum (R8 bug fix).
    l += __shfl_xor(l, 16);
    l += __shfl_xor(l, 32);

    // write chunk partial: P[bh][qt16][ch][row16][36]
    float* dst = P + ((((size_t)bh * NQT16 + (ig0 >> 4)) * NCH + ch) * 16 + rr) * 36;
    *(f32x4*)(dst + quad * 4)      = o0;   // dims quad*4 .. +3
    *(f32x4*)(dst + 16 + quad * 4) = o1;   // dims 16+quad*4 .. +3
    if (quad == 0) { dst[32] = m; dst[33] = l; }
}

// ---------------------------------------------------------------------------
// Kernel 3: chunk-merge (flash-decoding) + mean-pool + o-proj + LN + f-proj
// + SiLU. Block per (t, b), 128 threads. (unchanged — proven)
// ---------------------------------------------------------------------------
__global__ __launch_bounds__(128) void final_kernel(
    const float* __restrict__ P,
    const float* __restrict__ o_w,    const float* __restrict__ o_b,
    const float* __restrict__ f_ln_w, const float* __restrict__ f_ln_b,
    const float* __restrict__ f_w,    const float* __restrict__ f_b,
    float* __restrict__ out, int C, int NCH)
{
    const int t = blockIdx.x;
    const int b = blockIdx.y;
    const int d = threadIdx.x;     // 0..127
    const int h  = d >> 5;         // head
    const int hd = d & 31;         // dim within head
    const int bh = b * NHH + h;

    __shared__ float ms[HIDD];
    __shared__ float lnbuf[HIDD];
    __shared__ float w1[2], w2[2];

    const int jmax = (t + 1) * NF;
    const int nch  = min(NCH, (jmax + C - 1) / C);

    float acc = 0.0f;
    #pragma unroll
    for (int f = 0; f < NF; f++) {
        const int row = t * NF + f;
        const int qt16 = row >> 4;
        const int r    = row & 15;
        float M = -1e30f, L = 0.0f, O = 0.0f;
        for (int c = 0; c < nch; c++) {
            const float* pr = P + ((((size_t)bh * NQT16 + qt16) * NCH + c) * 16 + r) * 36;
            const float mc = pr[32], lc = pr[33], oc = pr[hd];
            const float mm = fmaxf(M, mc);
            const float sa = __expf(M - mm), sb = __expf(mc - mm);
            O = O * sa + oc * sb;
            L = L * sa + lc * sb;
            M = mm;
        }
        acc += O / L;
    }
    acc *= (1.0f / NF);
    ms[d] = acc;
    __syncthreads();

    float ov = o_b[d];
    for (int k = 0; k < HIDD; k++) ov += ms[k] * o_w[k * HIDD + d];

    float s1 = ov, s2 = ov * ov;
    #pragma unroll
    for (int m = 32; m >= 1; m >>= 1) { s1 += __shfl_xor(s1, m); s2 += __shfl_xor(s2, m); }
    if ((d & 63) == 0) { w1[d >> 6] = s1; w2[d >> 6] = s2; }
    __syncthreads();
    float S1 = w1[0] + w1[1], S2 = w2[0] + w2[1];
    float mu  = S1 * (1.0f / HIDD);
    float var = S2 * (1.0f / HIDD) - mu * mu;
    float r   = rsqrtf(var + EPSF);
    float lnv = (ov - mu) * r * f_ln_w[d] + f_ln_b[d];
    lnbuf[d] = lnv;
    __syncthreads();

    float fv = f_b[d];
    for (int k = 0; k < HIDD; k++) fv += lnbuf[k] * f_w[k * HIDD + d];
    fv = fv / (1.0f + __expf(-fv));

    out[((size_t)(b * TT + t)) * FDD + d] = fv;
}

// ---------------------------------------------------------------------------
extern "C" void kernel_launch(void* const* d_in, const int* in_sizes, int n_in,
                              void* d_out, int out_size, void* d_ws, size_t ws_size,
                              hipStream_t stream)
{
    const float* x      = (const float*)d_in[0];
    const float* g_ln_w = (const float*)d_in[1];
    const float* g_ln_b = (const float*)d_in[2];
    const float* g_w1   = (const float*)d_in[3];
    const float* g_b1   = (const float*)d_in[4];
    const float* g_w2   = (const float*)d_in[5];
    const float* g_b2   = (const float*)d_in[6];
    const float* q_w    = (const float*)d_in[7];
    const float* q_b    = (const float*)d_in[8];
    const float* k_w    = (const float*)d_in[9];
    const float* k_b    = (const float*)d_in[10];
    const float* v_w    = (const float*)d_in[11];
    const float* v_b    = (const float*)d_in[12];
    const float* o_w    = (const float*)d_in[13];
    const float* o_b    = (const float*)d_in[14];
    const float* f_ln_w = (const float*)d_in[15];
    const float* f_ln_b = (const float*)d_in[16];
    const float* f_w    = (const float*)d_in[17];
    const float* f_b    = (const float*)d_in[18];

    const size_t ntok = (size_t)BB * NHH * LL * HDD;     // 786432 bf16 elems/array
    unsigned short* Qh  = (unsigned short*)d_ws;
    unsigned short* Ql  = Qh  + ntok;
    unsigned short* Kh  = Ql  + ntok;
    unsigned short* Kl  = Kh  + ntok;
    unsigned short* Vth = Kl  + ntok;
    unsigned short* Vtl = Vth + ntok;
    float* Pw = (float*)(Vtl + ntok);                    // split-K partials

    // chunk count from available scratch (deterministic per ws_size);
    // C a multiple of 64 (LL is too) keeps 64-key-tile over-reads inside LL.
    const long long bf_floats = (long long)(6 * ntok) / 2;          // 2359296
    const long long unit = 8LL * NQT16 * 16 * 36;                   // 884736 fl/chunk
    long long avail = (long long)(ws_size / 4) - bf_floats - 4096;  // slack
    int NCH = (int)(avail / unit);
    if (NCH > 6) NCH = 6;
    if (NCH < 1) NCH = 1;
    const int C = 64 * ((LL + 64 * NCH - 1) / (64 * NCH));          // keys/chunk

    gate_qkv_kernel<<<(BB * LL) / 4, 128, 0, stream>>>(
        x, g_ln_w, g_ln_b, g_w1, g_b1, g_w2, g_b2,
        q_w, q_b, k_w, k_b, v_w, v_b, Qh, Ql, Kh, Kl, Vth, Vtl);

    attn_mfma<<<(LL / 64) * NCH * BB * NHH, 256, 0, stream>>>(
        Qh, Ql, Kh, Kl, Vth, Vtl, Pw, C, NCH);

    final_kernel<<<dim3(TT, BB), 128, 0, stream>>>(
        Pw, o_w, o_b, f_ln_w, f_ln_b, f_w, f_b, (float*)d_out, C, NCH);
}